// Round 1
// baseline (11510.226 us; speedup 1.0000x reference)
//
#include <hip/hip_runtime.h>

typedef unsigned short u16;
typedef float f32x4 __attribute__((ext_vector_type(4)));
typedef __bf16 bf16x8 __attribute__((ext_vector_type(8)));
typedef u16 u16x8 __attribute__((ext_vector_type(8)));

#define DEVFN __device__ __forceinline__

// ---- constants ----
// B=8, S=256, V=32000, H=1024, HEADS=8, HD=128, N_HIGH=4, N_LOW=16, RATIO=4
// block = 16 timesteps; 16 blocks total.

DEVFN u16 f2bf(float f) {
  unsigned u = __builtin_bit_cast(unsigned, f);
  unsigned r = u + 0x7FFFu + ((u >> 16) & 1u);   // RNE
  return (u16)(r >> 16);
}

DEVFN bf16x8 cvt8(const float* p) {
  float4 f0 = *reinterpret_cast<const float4*>(p);
  float4 f1 = *reinterpret_cast<const float4*>(p + 4);
  u16x8 u;
  u[0] = f2bf(f0.x); u[1] = f2bf(f0.y); u[2] = f2bf(f0.z); u[3] = f2bf(f0.w);
  u[4] = f2bf(f1.x); u[5] = f2bf(f1.y); u[6] = f2bf(f1.z); u[7] = f2bf(f1.w);
  return __builtin_bit_cast(bf16x8, u);
}

// ---------------- generic GEMM: OUT[M][N] = X[M][K] @ W[N][K+kwoff]^T (+Cadd) ---------
// bf16 MFMA 16x16x32, fp32 accumulate. 1 wave per block; wave tile = (16*MT) x (16*NT).
// Requires: M % (16*MT) == 0, N % (16*NT) == 0, K % 32 == 0. ABF=1: X is bf16 (u16 bits).
template<int MT, int NT, int ABF>
__global__ __launch_bounds__(64) void gemm_tn(const void* __restrict__ Xv, int ldx,
                                              const float* __restrict__ W, int ldw, int kwoff,
                                              const float* __restrict__ Cadd,
                                              float* __restrict__ OUT, int ldo, int K) {
  int lane = threadIdx.x;
  int n0 = blockIdx.x * (16 * NT);
  int m0 = blockIdx.y * (16 * MT);
  int lr = lane & 15;
  int kk = (lane >> 4) << 3;   // 0,8,16,24

  f32x4 acc[MT][NT];
#pragma unroll
  for (int mi = 0; mi < MT; ++mi)
#pragma unroll
    for (int ni = 0; ni < NT; ++ni) acc[mi][ni] = f32x4{0.f, 0.f, 0.f, 0.f};

  const float* wp[NT];
#pragma unroll
  for (int ni = 0; ni < NT; ++ni)
    wp[ni] = W + (size_t)(n0 + ni * 16 + lr) * (size_t)ldw + kwoff + kk;

  const float* xf[MT];
  const u16* xb[MT];
#pragma unroll
  for (int mi = 0; mi < MT; ++mi) {
    size_t ro = (size_t)(m0 + mi * 16 + lr) * (size_t)ldx + kk;
    if constexpr (ABF) xb[mi] = ((const u16*)Xv) + ro;
    else xf[mi] = ((const float*)Xv) + ro;
  }

  for (int k0 = 0; k0 < K; k0 += 32) {
    bf16x8 bfr[NT];
#pragma unroll
    for (int ni = 0; ni < NT; ++ni) bfr[ni] = cvt8(wp[ni] + k0);
#pragma unroll
    for (int mi = 0; mi < MT; ++mi) {
      bf16x8 a;
      if constexpr (ABF) a = *reinterpret_cast<const bf16x8*>(xb[mi] + k0);
      else a = cvt8(xf[mi] + k0);
#pragma unroll
      for (int ni = 0; ni < NT; ++ni)
        acc[mi][ni] = __builtin_amdgcn_mfma_f32_16x16x32_bf16(a, bfr[ni], acc[mi][ni], 0, 0, 0);
    }
  }

  int rbase = (lane >> 4) << 2;
#pragma unroll
  for (int mi = 0; mi < MT; ++mi)
#pragma unroll
    for (int ni = 0; ni < NT; ++ni)
#pragma unroll
      for (int rr = 0; rr < 4; ++rr) {
        size_t o = (size_t)(m0 + mi * 16 + rbase + rr) * (size_t)ldo + (size_t)(n0 + ni * 16 + lr);
        float v = acc[mi][ni][rr];
        if (Cadd) v += Cadd[o];
        OUT[o] = v;
      }
}

// ---------------- embeds: out[R(t,b)][h] = emb[ids[b][t]][h] + pos[t][h] -------------
// R(t,b) = (w*16 + o*4 + g)*8 + b  with w=t/16, g=(t%16)/4, o=t%4.
__global__ void embed_kernel(const int* __restrict__ ids, const float* __restrict__ emb,
                             const float* __restrict__ pos, float* __restrict__ out) {
  int idx = blockIdx.x * 256 + threadIdx.x;   // 2048 rows * 256 float4
  int h4 = idx & 255;
  int rb = idx >> 8;
  int t = rb >> 3, b = rb & 7;
  int w = t >> 4, lsp = t & 15, g = lsp >> 2, o = lsp & 3;
  int R = ((w << 4) + (o << 2) + g) * 8 + b;
  int tok = ids[b * 256 + t];
  const float4 e4 = reinterpret_cast<const float4*>(emb)[(size_t)tok * 256 + h4];
  const float4 p4 = reinterpret_cast<const float4*>(pos)[(size_t)t * 256 + h4];
  float4 v;
  v.x = e4.x + p4.x; v.y = e4.y + p4.y; v.z = e4.z + p4.z; v.w = e4.w + p4.w;
  reinterpret_cast<float4*>(out)[(size_t)R * 256 + h4] = v;
}

// ---------------- GRU gate: h = (1-z)*n + z*h  (in-place state update) ---------------
__global__ void gru_gate(const float* __restrict__ gx, const float* __restrict__ gh,
                         const float* __restrict__ bih, const float* __restrict__ bhh,
                         float* __restrict__ h, float* __restrict__ extra, int M) {
  int idx = blockIdx.x * 256 + threadIdx.x;
  if (idx >= M * 1024) return;
  int m = idx >> 10, j = idx & 1023;
  const float* gxr = gx + (size_t)m * 3072;
  const float* ghr = gh + (size_t)m * 3072;
  float xr = gxr[j] + bih[j];
  float xz = gxr[1024 + j] + bih[1024 + j];
  float xn = gxr[2048 + j] + bih[2048 + j];
  float hr = ghr[j] + bhh[j];
  float hz = ghr[1024 + j] + bhh[1024 + j];
  float hn = ghr[2048 + j] + bhh[2048 + j];
  float r = 1.f / (1.f + expf(-(xr + hr)));
  float z = 1.f / (1.f + expf(-(xz + hz)));
  float n = tanhf(xn + r * hn);
  float hv = h[idx];
  float o = (1.f - z) * n + z * hv;
  h[idx] = o;
  if (extra) extra[idx] = o;
}

// ---------------- inp = gelu(einp + hcpart + bin) (tanh-approx gelu, jax default) ----
__global__ void inp_kernel(const float* __restrict__ einpB, const float* __restrict__ hcp,
                           const float* __restrict__ bin, float* __restrict__ inpb) {
  int idx = blockIdx.x * 256 + threadIdx.x;   // 128*1024
  int r = idx >> 10, j = idx & 1023;
  int g = (r >> 3) & 3, b = r & 7;
  float x = einpB[idx] + hcp[(size_t)((g << 3) + b) * 1024 + j] + bin[j];
  float t = tanhf(0.7978845608028654f * (x + 0.044715f * x * x * x));
  inpb[idx] = 0.5f * x * (1.f + t);
}

// ---------------- attention (4 hist slots, 8 heads, HD=128) --------------------------
__global__ void attn_kernel(const float* __restrict__ qb, const float* __restrict__ Kc,
                            const float* __restrict__ Vc, float* __restrict__ ctx) {
  int r = blockIdx.x;        // 0..127  (r = s'*8+b, s' = o*4+g)
  int sp = r >> 3;
  int g = sp & 3;
  int b = r & 7;
  int lane = threadIdx.x;    // 64 threads = 1 wave
  __shared__ float aw[8][4];
  if (lane < 32) {
    int head = lane >> 2, t = lane & 3;
    float s = 0.f;
    if (t <= g) {
      const float* qp = qb + (size_t)r * 1024 + head * 128;
      const float* kp = Kc + (size_t)(t * 8 + b) * 1024 + head * 128;
      for (int d = 0; d < 128; ++d) s += qp[d] * kp[d];
      s *= 0.08838834764831845f;   // 1/sqrt(128)
    }
    float sc[4];
    sc[0] = __shfl(s, (head << 2) + 0);
    sc[1] = __shfl(s, (head << 2) + 1);
    sc[2] = __shfl(s, (head << 2) + 2);
    sc[3] = __shfl(s, (head << 2) + 3);
    if (t == 0) {
      float mx = -1e30f;
      for (int u = 0; u <= g; ++u) mx = fmaxf(mx, sc[u]);
      float p[4] = {0.f, 0.f, 0.f, 0.f};
      float den = 0.f;
      for (int u = 0; u <= g; ++u) { p[u] = expf(sc[u] - mx); den += p[u]; }
      float inv = 1.f / den;
      for (int u = 0; u < 4; ++u) aw[head][u] = (u <= g) ? p[u] * inv : 0.f;
    }
  }
  __syncthreads();
  for (int idx = lane; idx < 1024; idx += 64) {
    int head = idx >> 7;
    float acc = 0.f;
#pragma unroll
    for (int t = 0; t < 4; ++t) acc += aw[head][t] * Vc[(size_t)(t * 8 + b) * 1024 + idx];
    ctx[(size_t)r * 1024 + idx] = acc;
  }
}

// ---------------- layernorm -> bf16 Y row (row = b*256 + t) --------------------------
__global__ void ln_kernel(const float* __restrict__ xr, const float* __restrict__ g_,
                          const float* __restrict__ b_, u16* __restrict__ Ybf, int w) {
  int r = blockIdx.x;        // 0..127
  int tid = threadIdx.x;     // 256
  const float* x = xr + (size_t)r * 1024;
  float s = 0.f, s2 = 0.f;
  for (int j = tid; j < 1024; j += 256) { float v = x[j]; s += v; s2 += v * v; }
  for (int off = 32; off; off >>= 1) { s += __shfl_xor(s, off); s2 += __shfl_xor(s2, off); }
  __shared__ float rs[4], rs2[4], mv[2];
  int wv = tid >> 6;
  if ((tid & 63) == 0) { rs[wv] = s; rs2[wv] = s2; }
  __syncthreads();
  if (tid == 0) {
    float S = rs[0] + rs[1] + rs[2] + rs[3];
    float S2 = rs2[0] + rs2[1] + rs2[2] + rs2[3];
    float mu = S * (1.f / 1024.f);
    float var = S2 * (1.f / 1024.f) - mu * mu;
    mv[0] = mu;
    mv[1] = rsqrtf(var + 1e-5f);
  }
  __syncthreads();
  float mu = mv[0], rstd = mv[1];
  int sp = r >> 3, b = r & 7;
  int g = sp & 3, o = sp >> 2;
  int t = w * 16 + g * 4 + o;
  u16* yrow = Ybf + (size_t)(b * 256 + t) * 1024;
  for (int j = tid; j < 1024; j += 256) {
    float v = (x[j] - mu) * rstd * g_[j] + b_[j];
    yrow[j] = f2bf(v);
  }
}

extern "C" void kernel_launch(void* const* d_in, const int* in_sizes, int n_in,
                              void* d_out, int out_size, void* d_ws, size_t ws_size,
                              hipStream_t stream) {
  const int* ids = (const int*)d_in[0];
  const float* emb = (const float*)d_in[1];
  const float* pos = (const float*)d_in[2];
  const float* Wih_h = (const float*)d_in[3];
  const float* bih_h = (const float*)d_in[4];
  const float* Whh_h = (const float*)d_in[5];
  const float* bhh_h = (const float*)d_in[6];
  const float* Win = (const float*)d_in[7];
  const float* bin_ = (const float*)d_in[8];
  const float* Wq = (const float*)d_in[9];
  const float* Wk = (const float*)d_in[10];
  const float* Wv = (const float*)d_in[11];
  const float* Wo = (const float*)d_in[12];
  const float* Wih_l = (const float*)d_in[13];
  const float* bih_l = (const float*)d_in[14];
  const float* Whh_l = (const float*)d_in[15];
  const float* bhh_l = (const float*)d_in[16];
  const float* ln_g = (const float*)d_in[17];
  const float* ln_b = (const float*)d_in[18];
  const float* Wout = (const float*)d_in[19];
  float* out = (float*)d_out;

  // ---- workspace layout (floats) ----
  float* ws = (float*)d_ws;
  float* hs = ws;                       // [2][4][8][1024] = 65536   (layer-major)
  float* lsb = hs + 65536;              // [2][16][8][1024] = 262144 (layer-major, slot'=o*4+g)
  float* hist = lsb + 262144;           // [4][8][1024] = 32768
  float* embeds = hist + 32768;         // 2048*1024
  float* einp = embeds + 2097152;       // 2048*1024
  float* Kc = einp + 2097152;           // 32*1024
  float* Vc = Kc + 32768;               // 32*1024
  float* hcp = Vc + 32768;              // 32*1024
  float* gxh = hcp + 32768;             // 32*3072
  float* ghh = gxh + 98304;             // 32*3072
  float* inpb = ghh + 98304;            // 128*1024
  float* qb = inpb + 131072;            // 128*1024
  float* ctxb = qb + 131072;            // 128*1024
  float* x2 = ctxb + 131072;            // 128*1024
  float* gxl = x2 + 131072;             // 128*3072
  float* ghl = gxl + 393216;            // 128*3072
  u16* Ybf = (u16*)(ghl + 393216);      // 2048*1024 bf16

  // zero recurrent state (hs, ls, hist are contiguous at ws start)
  (void)hipMemsetAsync(ws, 0, (size_t)(65536 + 262144 + 32768) * sizeof(float), stream);

  // prologue: embeddings, and e-part of Win for all 2048 rows
  embed_kernel<<<2048, 256, 0, stream>>>(ids, emb, pos, embeds);
  gemm_tn<4, 4, 0><<<dim3(1024 / 64, 2048 / 64), 64, 0, stream>>>(
      embeds, 1024, Win, 2048, 0, nullptr, einp, 1024, 1024);

  const int L = 3072 * 1024;   // per-layer weight stride
  for (int w = 0; w < 16; ++w) {
    const float* eblk = embeds + (size_t)w * 131072;   // 128 rows; first 32 are o=0 (high steps)
    // ---- high module, layer 0 ----
    gemm_tn<2, 1, 0><<<dim3(192, 1), 64, 0, stream>>>(hs, 1024, Whh_h, 1024, 0, nullptr, ghh, 3072, 1024);
    gemm_tn<2, 1, 0><<<dim3(192, 1), 64, 0, stream>>>(eblk, 1024, Wih_h, 1024, 0, nullptr, gxh, 3072, 1024);
    gru_gate<<<128, 256, 0, stream>>>(gxh, ghh, bih_h, bhh_h, hs, nullptr, 32);
    // ---- high module, layer 1 ----
    gemm_tn<2, 1, 0><<<dim3(192, 1), 64, 0, stream>>>(hs + 32768, 1024, Whh_h + L, 1024, 0, nullptr, ghh, 3072, 1024);
    gemm_tn<2, 1, 0><<<dim3(192, 1), 64, 0, stream>>>(hs, 1024, Wih_h + L, 1024, 0, nullptr, gxh, 3072, 1024);
    gru_gate<<<128, 256, 0, stream>>>(gxh, ghh, bih_h + 3072, bhh_h + 3072, hs + 32768, hist, 32);
    // ---- K, V, hc-part of Win from the 4 fresh hist rows ----
    gemm_tn<2, 1, 0><<<dim3(64, 1), 64, 0, stream>>>(hist, 1024, Wk, 1024, 0, nullptr, Kc, 1024, 1024);
    gemm_tn<2, 1, 0><<<dim3(64, 1), 64, 0, stream>>>(hist, 1024, Wv, 1024, 0, nullptr, Vc, 1024, 1024);
    gemm_tn<2, 1, 0><<<dim3(64, 1), 64, 0, stream>>>(hist, 1024, Win, 2048, 1024, nullptr, hcp, 1024, 1024);
    // ---- inp = gelu(e-part + hc-part + bin), then q ----
    inp_kernel<<<512, 256, 0, stream>>>(einp + (size_t)w * 131072, hcp, bin_, inpb);
    gemm_tn<4, 2, 0><<<dim3(32, 2), 64, 0, stream>>>(inpb, 1024, Wq, 1024, 0, nullptr, qb, 1024, 1024);
    // ---- attention + output proj (+inp residual) -> x2 ----
    attn_kernel<<<128, 64, 0, stream>>>(qb, Kc, Vc, ctxb);
    gemm_tn<4, 2, 0><<<dim3(32, 2), 64, 0, stream>>>(ctxb, 1024, Wo, 1024, 0, inpb, x2, 1024, 1024);
    // ---- low GRU, layer 0 (16 independent slots x 8 batch = 128 rows) ----
    gemm_tn<4, 2, 0><<<dim3(96, 2), 64, 0, stream>>>(lsb, 1024, Whh_l, 1024, 0, nullptr, ghl, 3072, 1024);
    gemm_tn<4, 2, 0><<<dim3(96, 2), 64, 0, stream>>>(x2, 1024, Wih_l, 1024, 0, nullptr, gxl, 3072, 1024);
    gru_gate<<<512, 256, 0, stream>>>(gxl, ghl, bih_l, bhh_l, lsb, nullptr, 128);
    // ---- low GRU, layer 1 ----
    gemm_tn<4, 2, 0><<<dim3(96, 2), 64, 0, stream>>>(lsb + 131072, 1024, Whh_l + L, 1024, 0, nullptr, ghl, 3072, 1024);
    gemm_tn<4, 2, 0><<<dim3(96, 2), 64, 0, stream>>>(lsb, 1024, Wih_l + L, 1024, 0, nullptr, gxl, 3072, 1024);
    gru_gate<<<512, 256, 0, stream>>>(gxl, ghl, bih_l + 3072, bhh_l + 3072, lsb + 131072, nullptr, 128);
    // ---- layernorm -> bf16 Y ----
    ln_kernel<<<128, 256, 0, stream>>>(lsb + 131072, ln_g, ln_b, Ybf, w);
  }

  // ---- final projection: (2048 x 1024) @ Wout^T -> (2048 x 32000) ----
  gemm_tn<4, 4, 1><<<dim3(32000 / 64, 2048 / 64), 64, 0, stream>>>(
      Ybf, 1024, Wout, 1024, 0, nullptr, out, 32000, 1024);
}

// Round 2
// 2144.382 us; speedup vs baseline: 5.3676x; 5.3676x over previous
//
#include <hip/hip_runtime.h>

typedef unsigned short u16;
typedef float f32x4 __attribute__((ext_vector_type(4)));
typedef __bf16 bf16x8 __attribute__((ext_vector_type(8)));
typedef u16 u16x8 __attribute__((ext_vector_type(8)));

#define DEVFN __device__ __forceinline__

// B=8, S=256, V=32000, H=1024, HEADS=8, HD=128, N_HIGH=4, N_LOW=16, RATIO=4
// Block = 16 timesteps; 16 blocks. Row layout R(t,b) = (w*16 + o*4 + g)*8 + b,
// w=t/16, g=(t%16)/4, o=t%4. High rows = first 32 of each 128-row block.

DEVFN u16 f2bf(float f) {
  unsigned u = __builtin_bit_cast(unsigned, f);
  unsigned r = u + 0x7FFFu + ((u >> 16) & 1u);   // RNE
  return (u16)(r >> 16);
}

DEVFN bf16x8 cvt8(const float* p) {
  float4 f0 = *reinterpret_cast<const float4*>(p);
  float4 f1 = *reinterpret_cast<const float4*>(p + 4);
  u16x8 u;
  u[0] = f2bf(f0.x); u[1] = f2bf(f0.y); u[2] = f2bf(f0.z); u[3] = f2bf(f0.w);
  u[4] = f2bf(f1.x); u[5] = f2bf(f1.y); u[6] = f2bf(f1.z); u[7] = f2bf(f1.w);
  return __builtin_bit_cast(bf16x8, u);
}

DEVFN bf16x8 ldbf(const u16* p) { return *reinterpret_cast<const bf16x8*>(p); }
DEVFN float sigm(float x) { return 1.f / (1.f + expf(-x)); }

// ---------------- generic GEMM: OUT[M][N] = A[M][K](bf16) @ W[N][K]^T (+Cadd) --------
// KW waves split K, LDS reduce. wbf: W is bf16 (1) or fp32 (0).
template<int MT, int NT, int KW>
__global__ __launch_bounds__(64 * KW) void gemm2(
    const u16* __restrict__ A, int lda,
    const void* __restrict__ Wp, int ldw, int kwoff, int wbf,
    const float* __restrict__ Cadd, int ldc,
    float* __restrict__ OUT, u16* __restrict__ OUTbf, int ldo, int K) {
  int tid = threadIdx.x;
  int kw = tid >> 6;
  int lane = tid & 63;
  int lr = lane & 15;
  int kk = (lane >> 4) << 3;
  int n0 = blockIdx.x * (16 * NT);
  int m0 = blockIdx.y * (16 * MT);
  int KP = K / KW;
  int kb = kw * KP + kk;

  f32x4 acc[MT][NT];
#pragma unroll
  for (int mi = 0; mi < MT; ++mi)
#pragma unroll
    for (int ni = 0; ni < NT; ++ni) acc[mi][ni] = f32x4{0.f, 0.f, 0.f, 0.f};

  const u16* ap[MT];
#pragma unroll
  for (int mi = 0; mi < MT; ++mi) ap[mi] = A + (size_t)(m0 + mi * 16 + lr) * (size_t)lda + kb;

  if (wbf) {
    const u16* wb[NT];
#pragma unroll
    for (int ni = 0; ni < NT; ++ni)
      wb[ni] = (const u16*)Wp + (size_t)(n0 + ni * 16 + lr) * (size_t)ldw + kwoff + kb;
    for (int k0 = 0; k0 < KP; k0 += 32) {
      bf16x8 wv[NT];
#pragma unroll
      for (int ni = 0; ni < NT; ++ni) wv[ni] = ldbf(wb[ni] + k0);
#pragma unroll
      for (int mi = 0; mi < MT; ++mi) {
        bf16x8 a = ldbf(ap[mi] + k0);
#pragma unroll
        for (int ni = 0; ni < NT; ++ni)
          acc[mi][ni] = __builtin_amdgcn_mfma_f32_16x16x32_bf16(a, wv[ni], acc[mi][ni], 0, 0, 0);
      }
    }
  } else {
    const float* wf[NT];
#pragma unroll
    for (int ni = 0; ni < NT; ++ni)
      wf[ni] = (const float*)Wp + (size_t)(n0 + ni * 16 + lr) * (size_t)ldw + kwoff + kb;
    for (int k0 = 0; k0 < KP; k0 += 32) {
      bf16x8 wv[NT];
#pragma unroll
      for (int ni = 0; ni < NT; ++ni) wv[ni] = cvt8(wf[ni] + k0);
#pragma unroll
      for (int mi = 0; mi < MT; ++mi) {
        bf16x8 a = ldbf(ap[mi] + k0);
#pragma unroll
        for (int ni = 0; ni < NT; ++ni)
          acc[mi][ni] = __builtin_amdgcn_mfma_f32_16x16x32_bf16(a, wv[ni], acc[mi][ni], 0, 0, 0);
      }
    }
  }

  if constexpr (KW > 1) {
    __shared__ f32x4 red[KW][MT * NT][64];
#pragma unroll
    for (int mi = 0; mi < MT; ++mi)
#pragma unroll
      for (int ni = 0; ni < NT; ++ni) red[kw][mi * NT + ni][lane] = acc[mi][ni];
    __syncthreads();
    if (kw) return;
    for (int w2 = 1; w2 < KW; ++w2)
#pragma unroll
      for (int mi = 0; mi < MT; ++mi)
#pragma unroll
        for (int ni = 0; ni < NT; ++ni) acc[mi][ni] += red[w2][mi * NT + ni][lane];
  }

  int rb = (lane >> 4) << 2;
#pragma unroll
  for (int mi = 0; mi < MT; ++mi)
#pragma unroll
    for (int ni = 0; ni < NT; ++ni)
#pragma unroll
      for (int rr = 0; rr < 4; ++rr) {
        int row = m0 + mi * 16 + rb + rr;
        int col = n0 + ni * 16 + lr;
        size_t o = (size_t)row * (size_t)ldo + col;
        float v = acc[mi][ni][rr];
        if (Cadd) v += Cadd[(size_t)row * (size_t)ldc + col];
        if (OUT) OUT[o] = v;
        if (OUTbf) OUTbf[o] = f2bf(v);
      }
}

// ---------------- fused GRU layer: gates GEMM + gate math + state update ------------
// g = X@Wih^T + H@Whh^T (r,z fused; n kept split for r*hn). Weights [3072][1024].
template<int MT, int KW>
__global__ __launch_bounds__(64 * KW) void gru_fused(
    const u16* __restrict__ Xbf, const u16* __restrict__ Hbf,
    const float* __restrict__ Hold,
    const void* __restrict__ Wih, const void* __restrict__ Whh, int wbf,
    const float* __restrict__ bih, const float* __restrict__ bhh,
    float* __restrict__ Hnew, u16* __restrict__ HnewBf, u16* __restrict__ histBf) {
  int tid = threadIdx.x;
  int kw = tid >> 6;
  int lane = tid & 63;
  int lr = lane & 15;
  int kk = (lane >> 4) << 3;
  int j0 = blockIdx.x * 16;
  int m0 = blockIdx.y * (16 * MT);
  const int KP = 1024 / KW;
  int kb = kw * KP + kk;

  f32x4 aR[MT], aZ[MT], aNX[MT], aNH[MT];
#pragma unroll
  for (int mi = 0; mi < MT; ++mi) {
    aR[mi] = f32x4{0.f, 0.f, 0.f, 0.f};
    aZ[mi] = f32x4{0.f, 0.f, 0.f, 0.f};
    aNX[mi] = f32x4{0.f, 0.f, 0.f, 0.f};
    aNH[mi] = f32x4{0.f, 0.f, 0.f, 0.f};
  }

  const u16* xp[MT];
  const u16* hp[MT];
#pragma unroll
  for (int mi = 0; mi < MT; ++mi) {
    size_t ro = (size_t)(m0 + mi * 16 + lr) * 1024 + kb;
    xp[mi] = Xbf + ro;
    hp[mi] = Hbf + ro;
  }

  size_t wro = (size_t)(j0 + lr) * 1024 + kb;
  if (wbf) {
    const u16* W1 = (const u16*)Wih;
    const u16* W2 = (const u16*)Whh;
    const u16 *pxr = W1 + wro, *pxz = W1 + wro + 1048576, *pxn = W1 + wro + 2097152;
    const u16 *phr = W2 + wro, *phz = W2 + wro + 1048576, *phn = W2 + wro + 2097152;
    for (int k0 = 0; k0 < KP; k0 += 32) {
      bf16x8 wxr = ldbf(pxr + k0), wxz = ldbf(pxz + k0), wxn = ldbf(pxn + k0);
      bf16x8 whr = ldbf(phr + k0), whz = ldbf(phz + k0), whn = ldbf(phn + k0);
#pragma unroll
      for (int mi = 0; mi < MT; ++mi) {
        bf16x8 ax = ldbf(xp[mi] + k0);
        bf16x8 ah = ldbf(hp[mi] + k0);
        aR[mi] = __builtin_amdgcn_mfma_f32_16x16x32_bf16(ax, wxr, aR[mi], 0, 0, 0);
        aR[mi] = __builtin_amdgcn_mfma_f32_16x16x32_bf16(ah, whr, aR[mi], 0, 0, 0);
        aZ[mi] = __builtin_amdgcn_mfma_f32_16x16x32_bf16(ax, wxz, aZ[mi], 0, 0, 0);
        aZ[mi] = __builtin_amdgcn_mfma_f32_16x16x32_bf16(ah, whz, aZ[mi], 0, 0, 0);
        aNX[mi] = __builtin_amdgcn_mfma_f32_16x16x32_bf16(ax, wxn, aNX[mi], 0, 0, 0);
        aNH[mi] = __builtin_amdgcn_mfma_f32_16x16x32_bf16(ah, whn, aNH[mi], 0, 0, 0);
      }
    }
  } else {
    const float* W1 = (const float*)Wih;
    const float* W2 = (const float*)Whh;
    const float *pxr = W1 + wro, *pxz = W1 + wro + 1048576, *pxn = W1 + wro + 2097152;
    const float *phr = W2 + wro, *phz = W2 + wro + 1048576, *phn = W2 + wro + 2097152;
    for (int k0 = 0; k0 < KP; k0 += 32) {
      bf16x8 wxr = cvt8(pxr + k0), wxz = cvt8(pxz + k0), wxn = cvt8(pxn + k0);
      bf16x8 whr = cvt8(phr + k0), whz = cvt8(phz + k0), whn = cvt8(phn + k0);
#pragma unroll
      for (int mi = 0; mi < MT; ++mi) {
        bf16x8 ax = ldbf(xp[mi] + k0);
        bf16x8 ah = ldbf(hp[mi] + k0);
        aR[mi] = __builtin_amdgcn_mfma_f32_16x16x32_bf16(ax, wxr, aR[mi], 0, 0, 0);
        aR[mi] = __builtin_amdgcn_mfma_f32_16x16x32_bf16(ah, whr, aR[mi], 0, 0, 0);
        aZ[mi] = __builtin_amdgcn_mfma_f32_16x16x32_bf16(ax, wxz, aZ[mi], 0, 0, 0);
        aZ[mi] = __builtin_amdgcn_mfma_f32_16x16x32_bf16(ah, whz, aZ[mi], 0, 0, 0);
        aNX[mi] = __builtin_amdgcn_mfma_f32_16x16x32_bf16(ax, wxn, aNX[mi], 0, 0, 0);
        aNH[mi] = __builtin_amdgcn_mfma_f32_16x16x32_bf16(ah, whn, aNH[mi], 0, 0, 0);
      }
    }
  }

  if constexpr (KW > 1) {
    __shared__ f32x4 red[KW][4 * MT][64];
#pragma unroll
    for (int mi = 0; mi < MT; ++mi) {
      red[kw][mi * 4 + 0][lane] = aR[mi];
      red[kw][mi * 4 + 1][lane] = aZ[mi];
      red[kw][mi * 4 + 2][lane] = aNX[mi];
      red[kw][mi * 4 + 3][lane] = aNH[mi];
    }
    __syncthreads();
    if (kw) return;
    for (int w2 = 1; w2 < KW; ++w2)
#pragma unroll
      for (int mi = 0; mi < MT; ++mi) {
        aR[mi] += red[w2][mi * 4 + 0][lane];
        aZ[mi] += red[w2][mi * 4 + 1][lane];
        aNX[mi] += red[w2][mi * 4 + 2][lane];
        aNH[mi] += red[w2][mi * 4 + 3][lane];
      }
  }

  int c = j0 + lr;
  float br = bih[c] + bhh[c];
  float bz = bih[1024 + c] + bhh[1024 + c];
  float bnx = bih[2048 + c];
  float bnh = bhh[2048 + c];
  int rb = (lane >> 4) << 2;
#pragma unroll
  for (int mi = 0; mi < MT; ++mi)
#pragma unroll
    for (int rr = 0; rr < 4; ++rr) {
      int row = m0 + mi * 16 + rb + rr;
      float r = sigm(aR[mi][rr] + br);
      float z = sigm(aZ[mi][rr] + bz);
      float n = tanhf(aNX[mi][rr] + bnx + r * (aNH[mi][rr] + bnh));
      size_t o = (size_t)row * 1024 + c;
      float hv = (1.f - z) * n + z * Hold[o];
      Hnew[o] = hv;
      u16 hb = f2bf(hv);
      HnewBf[o] = hb;
      if (histBf) histBf[o] = hb;
    }
}

// ---------------- weight fp32 -> bf16 pack: dst[rows][cols] = src[r][col_off+c] -----
__global__ void cvt_w(const float* __restrict__ src, int src_ld, int col_off,
                      u16* __restrict__ dst, int log2c) {
  size_t idx = ((size_t)blockIdx.x * 256 + threadIdx.x) * 8;
  size_t row = idx >> log2c;
  int col = (int)(idx & ((1u << log2c) - 1));
  const float* s = src + row * (size_t)src_ld + col_off + col;
  *reinterpret_cast<u16x8*>(dst + idx) = __builtin_bit_cast(u16x8, cvt8(s));
}

// ---------------- embeds (bf16): out[R(t,b)][h] = emb[ids[b][t]][h] + pos[t][h] -----
__global__ void embed_kernel(const int* __restrict__ ids, const float* __restrict__ emb,
                             const float* __restrict__ pos, u16* __restrict__ out) {
  int idx = blockIdx.x * 256 + threadIdx.x;   // 2048 rows * 128 groups of 8
  int e8 = (idx & 127) << 3;
  int rb = idx >> 7;
  int t = rb >> 3, b = rb & 7;
  int w = t >> 4, lsp = t & 15, g = lsp >> 2, o = lsp & 3;
  int R = ((w << 4) + (o << 2) + g) * 8 + b;
  int tok = ids[b * 256 + t];
  const float* ep = emb + (size_t)tok * 1024 + e8;
  const float* pp = pos + (size_t)t * 1024 + e8;
  float v[8];
#pragma unroll
  for (int i = 0; i < 8; ++i) v[i] = ep[i] + pp[i];
  u16x8 u;
#pragma unroll
  for (int i = 0; i < 8; ++i) u[i] = f2bf(v[i]);
  *reinterpret_cast<u16x8*>(out + (size_t)R * 1024 + e8) = u;
}

// ---------------- inp = gelu(einp + hc + bin); fp32 + bf16 --------------------------
__global__ void inp_kernel(const float* __restrict__ einpB, const float* __restrict__ kvh,
                           const float* __restrict__ bin, float* __restrict__ inpb,
                           u16* __restrict__ inpbf) {
  int idx = blockIdx.x * 256 + threadIdx.x;   // 128*1024
  int r = idx >> 10, j = idx & 1023;
  int g = (r >> 3) & 3, b = r & 7;
  float x = einpB[idx] + kvh[(size_t)((g << 3) + b) * 3072 + 2048 + j] + bin[j];
  float t = tanhf(0.7978845608028654f * (x + 0.044715f * x * x * x));
  float v = 0.5f * x * (1.f + t);
  inpb[idx] = v;
  inpbf[idx] = f2bf(v);
}

// ---------------- attention (4 slots, 8 heads, HD=128); ctx -> bf16 -----------------
__global__ void attn_kernel(const float* __restrict__ qb, const float* __restrict__ kvh,
                            u16* __restrict__ ctxbf) {
  int r = blockIdx.x;        // r = (o*4+g)*8+b
  int sp = r >> 3;
  int g = sp & 3;
  int b = r & 7;
  int lane = threadIdx.x;
  __shared__ float aw[8][4];
  if (lane < 32) {
    int head = lane >> 2, t = lane & 3;
    float s = 0.f;
    if (t <= g) {
      const float* qp = qb + (size_t)r * 1024 + head * 128;
      const float* kp = kvh + (size_t)(t * 8 + b) * 3072 + head * 128;
      for (int d = 0; d < 128; ++d) s += qp[d] * kp[d];
      s *= 0.08838834764831845f;
    }
    float sc[4];
    sc[0] = __shfl(s, (head << 2) + 0);
    sc[1] = __shfl(s, (head << 2) + 1);
    sc[2] = __shfl(s, (head << 2) + 2);
    sc[3] = __shfl(s, (head << 2) + 3);
    if (t == 0) {
      float mx = -1e30f;
      for (int u = 0; u <= g; ++u) mx = fmaxf(mx, sc[u]);
      float p[4] = {0.f, 0.f, 0.f, 0.f};
      float den = 0.f;
      for (int u = 0; u <= g; ++u) { p[u] = expf(sc[u] - mx); den += p[u]; }
      float inv = 1.f / den;
      for (int u = 0; u < 4; ++u) aw[head][u] = (u <= g) ? p[u] * inv : 0.f;
    }
  }
  __syncthreads();
  for (int idx = lane; idx < 1024; idx += 64) {
    int head = idx >> 7;
    float acc = 0.f;
#pragma unroll
    for (int t = 0; t < 4; ++t) acc += aw[head][t] * kvh[(size_t)(t * 8 + b) * 3072 + 1024 + idx];
    ctxbf[(size_t)r * 1024 + idx] = f2bf(acc);
  }
}

// ---------------- layernorm -> bf16 Y row (row = b*256 + t) -------------------------
__global__ void ln_kernel(const float* __restrict__ xr, const float* __restrict__ g_,
                          const float* __restrict__ b_, u16* __restrict__ Ybf, int w) {
  int r = blockIdx.x;        // 0..127
  int tid = threadIdx.x;     // 256
  const float* x = xr + (size_t)r * 1024;
  float s = 0.f, s2 = 0.f;
  for (int j = tid; j < 1024; j += 256) { float v = x[j]; s += v; s2 += v * v; }
  for (int off = 32; off; off >>= 1) { s += __shfl_xor(s, off); s2 += __shfl_xor(s2, off); }
  __shared__ float rs[4], rs2[4], mv[2];
  int wv = tid >> 6;
  if ((tid & 63) == 0) { rs[wv] = s; rs2[wv] = s2; }
  __syncthreads();
  if (tid == 0) {
    float S = rs[0] + rs[1] + rs[2] + rs[3];
    float S2 = rs2[0] + rs2[1] + rs2[2] + rs2[3];
    float mu = S * (1.f / 1024.f);
    float var = S2 * (1.f / 1024.f) - mu * mu;
    mv[0] = mu;
    mv[1] = rsqrtf(var + 1e-5f);
  }
  __syncthreads();
  float mu = mv[0], rstd = mv[1];
  int sp = r >> 3, b = r & 7;
  int g = sp & 3, o = sp >> 2;
  int t = w * 16 + g * 4 + o;
  u16* yrow = Ybf + (size_t)(b * 256 + t) * 1024;
  for (int j = tid; j < 1024; j += 256) {
    float v = (x[j] - mu) * rstd * g_[j] + b_[j];
    yrow[j] = f2bf(v);
  }
}

extern "C" void kernel_launch(void* const* d_in, const int* in_sizes, int n_in,
                              void* d_out, int out_size, void* d_ws, size_t ws_size,
                              hipStream_t stream) {
  const int* ids = (const int*)d_in[0];
  const float* emb = (const float*)d_in[1];
  const float* pos = (const float*)d_in[2];
  const float* Wih_h = (const float*)d_in[3];
  const float* bih_h = (const float*)d_in[4];
  const float* Whh_h = (const float*)d_in[5];
  const float* bhh_h = (const float*)d_in[6];
  const float* Win = (const float*)d_in[7];
  const float* bin_ = (const float*)d_in[8];
  const float* Wq = (const float*)d_in[9];
  const float* Wk = (const float*)d_in[10];
  const float* Wv = (const float*)d_in[11];
  const float* Wo = (const float*)d_in[12];
  const float* Wih_l = (const float*)d_in[13];
  const float* bih_l = (const float*)d_in[14];
  const float* Whh_l = (const float*)d_in[15];
  const float* bhh_l = (const float*)d_in[16];
  const float* ln_g = (const float*)d_in[17];
  const float* ln_b = (const float*)d_in[18];
  const float* Wout = (const float*)d_in[19];
  float* out = (float*)d_out;

  // ---- workspace bump allocator ----
  size_t off = 0;
  char* wsb = (char*)d_ws;
  auto allocF = [&](size_t n) { float* p = (float*)(wsb + off); off += n * 4; return p; };
  auto allocU = [&](size_t n) { u16* p = (u16*)(wsb + off); off += n * 2; return p; };

  // zero-region: A-set state (fp32 then bf16), contiguous
  float* hs0A = allocF(32768);
  float* hs1A = allocF(32768);
  float* ls0A = allocF(131072);
  float* ls1A = allocF(131072);
  u16* hs0Ab = allocU(32768);
  u16* hs1Ab = allocU(32768);
  u16* ls0Ab = allocU(131072);
  u16* ls1Ab = allocU(131072);
  size_t zero_bytes = off;
  float* hs0B = allocF(32768);
  float* hs1B = allocF(32768);
  float* ls0B = allocF(131072);
  float* ls1B = allocF(131072);
  u16* hs0Bb = allocU(32768);
  u16* hs1Bb = allocU(32768);
  u16* ls0Bb = allocU(131072);
  u16* ls1Bb = allocU(131072);
  u16* histb = allocU(32768);
  u16* embB = allocU(2097152);
  float* einp = allocF(2097152);
  float* kvh = allocF(98304);
  float* inpb = allocF(131072);
  u16* inpbf = allocU(131072);
  float* qb = allocF(131072);
  u16* ctxbf = allocU(131072);
  u16* x2bf = allocU(131072);
  u16* Ybf = allocU(2097152);

  // weight packs (tiered by ws_size)
  const size_t WPACK_BYTES = (size_t)(25165824 + 2097152 + 1048576 + 1048576 + 3145728) * 2;
  bool packW = (off + WPACK_BYTES <= ws_size);
  u16 *WihHb = nullptr, *WhhHb = nullptr, *WihLb = nullptr, *WhhLb = nullptr;
  u16 *WinB = nullptr, *WqB = nullptr, *WoB = nullptr, *KVp = nullptr;
  if (packW) {
    WihHb = allocU(6291456);
    WhhHb = allocU(6291456);
    WihLb = allocU(6291456);
    WhhLb = allocU(6291456);
    WinB = allocU(2097152);
    WqB = allocU(1048576);
    WoB = allocU(1048576);
    KVp = allocU(3145728);
  }
  bool packWout = packW && (off + (size_t)32768000 * 2 <= ws_size);
  u16* WoutB = nullptr;
  if (packWout) WoutB = allocU(32768000);

  (void)hipMemsetAsync(d_ws, 0, zero_bytes, stream);

  // ---- prologue ----
  embed_kernel<<<1024, 256, 0, stream>>>(ids, emb, pos, embB);
  if (packW) {
    cvt_w<<<3072, 256, 0, stream>>>(Wih_h, 1024, 0, WihHb, 10);
    cvt_w<<<3072, 256, 0, stream>>>(Whh_h, 1024, 0, WhhHb, 10);
    cvt_w<<<3072, 256, 0, stream>>>(Wih_l, 1024, 0, WihLb, 10);
    cvt_w<<<3072, 256, 0, stream>>>(Whh_l, 1024, 0, WhhLb, 10);
    cvt_w<<<1024, 256, 0, stream>>>(Win, 2048, 0, WinB, 11);
    cvt_w<<<512, 256, 0, stream>>>(Wq, 1024, 0, WqB, 10);
    cvt_w<<<512, 256, 0, stream>>>(Wo, 1024, 0, WoB, 10);
    cvt_w<<<512, 256, 0, stream>>>(Wk, 1024, 0, KVp, 10);
    cvt_w<<<512, 256, 0, stream>>>(Wv, 1024, 0, KVp + 1048576, 10);
    cvt_w<<<512, 256, 0, stream>>>(Win, 2048, 1024, KVp + 2097152, 10);
  }
  if (packWout) cvt_w<<<16000, 256, 0, stream>>>(Wout, 1024, 0, WoutB, 10);

  // einp = embeds @ Win[:, :1024]^T for all 2048 rows
  gemm2<4, 4, 1><<<dim3(16, 32), 64, 0, stream>>>(
      embB, 1024, packW ? (const void*)WinB : (const void*)Win, 2048, 0, packW ? 1 : 0,
      nullptr, 0, einp, nullptr, 1024, 1024);

  const size_t LW = 3072 * 1024;
  const void* WihH0 = packW ? (const void*)WihHb : (const void*)Wih_h;
  const void* WihH1 = packW ? (const void*)(WihHb + LW) : (const void*)(Wih_h + LW);
  const void* WhhH0 = packW ? (const void*)WhhHb : (const void*)Whh_h;
  const void* WhhH1 = packW ? (const void*)(WhhHb + LW) : (const void*)(Whh_h + LW);
  const void* WihL0 = packW ? (const void*)WihLb : (const void*)Wih_l;
  const void* WihL1 = packW ? (const void*)(WihLb + LW) : (const void*)(Wih_l + LW);
  const void* WhhL0 = packW ? (const void*)WhhLb : (const void*)Whh_l;
  const void* WhhL1 = packW ? (const void*)(WhhLb + LW) : (const void*)(Whh_l + LW);
  int wbfW = packW ? 1 : 0;

  for (int w = 0; w < 16; ++w) {
    bool odd = w & 1;
    float* hs0i = odd ? hs0B : hs0A; float* hs0o = odd ? hs0A : hs0B;
    float* hs1i = odd ? hs1B : hs1A; float* hs1o = odd ? hs1A : hs1B;
    float* ls0i = odd ? ls0B : ls0A; float* ls0o = odd ? ls0A : ls0B;
    float* ls1i = odd ? ls1B : ls1A; float* ls1o = odd ? ls1A : ls1B;
    u16* hs0ib = odd ? hs0Bb : hs0Ab; u16* hs0ob = odd ? hs0Ab : hs0Bb;
    u16* hs1ib = odd ? hs1Bb : hs1Ab; u16* hs1ob = odd ? hs1Ab : hs1Bb;
    u16* ls0ib = odd ? ls0Bb : ls0Ab; u16* ls0ob = odd ? ls0Ab : ls0Bb;
    u16* ls1ib = odd ? ls1Bb : ls1Ab; u16* ls1ob = odd ? ls1Ab : ls1Bb;
    const u16* eblk = embB + (size_t)w * 131072;

    // high module (M=32 rows: g*8+b)
    gru_fused<2, 4><<<dim3(64, 1), 256, 0, stream>>>(
        eblk, hs0ib, hs0i, WihH0, WhhH0, wbfW, bih_h, bhh_h, hs0o, hs0ob, nullptr);
    gru_fused<2, 4><<<dim3(64, 1), 256, 0, stream>>>(
        hs0ob, hs1ib, hs1i, WihH1, WhhH1, wbfW, bih_h + 3072, bhh_h + 3072,
        hs1o, hs1ob, histb);
    // K | V | Win-hc from 4 fresh hist rows
    if (packW) {
      gemm2<2, 1, 4><<<dim3(192, 1), 256, 0, stream>>>(
          histb, 1024, KVp, 1024, 0, 1, nullptr, 0, kvh, nullptr, 3072, 1024);
    } else {
      gemm2<2, 1, 4><<<dim3(64, 1), 256, 0, stream>>>(
          histb, 1024, Wk, 1024, 0, 0, nullptr, 0, kvh, nullptr, 3072, 1024);
      gemm2<2, 1, 4><<<dim3(64, 1), 256, 0, stream>>>(
          histb, 1024, Wv, 1024, 0, 0, nullptr, 0, kvh + 1024, nullptr, 3072, 1024);
      gemm2<2, 1, 4><<<dim3(64, 1), 256, 0, stream>>>(
          histb, 1024, Win, 2048, 1024, 0, nullptr, 0, kvh + 2048, nullptr, 3072, 1024);
    }
    inp_kernel<<<512, 256, 0, stream>>>(einp + (size_t)w * 131072, kvh, bin_, inpb, inpbf);
    gemm2<2, 1, 2><<<dim3(64, 4), 128, 0, stream>>>(
        inpbf, 1024, packW ? (const void*)WqB : (const void*)Wq, 1024, 0, wbfW,
        nullptr, 0, qb, nullptr, 1024, 1024);
    attn_kernel<<<128, 64, 0, stream>>>(qb, kvh, ctxbf);
    gemm2<2, 1, 2><<<dim3(64, 4), 128, 0, stream>>>(
        ctxbf, 1024, packW ? (const void*)WoB : (const void*)Wo, 1024, 0, wbfW,
        inpb, 1024, nullptr, x2bf, 1024, 1024);
    // low module (M=128 rows: (o*4+g)*8+b)
    gru_fused<2, 4><<<dim3(64, 4), 256, 0, stream>>>(
        x2bf, ls0ib, ls0i, WihL0, WhhL0, wbfW, bih_l, bhh_l, ls0o, ls0ob, nullptr);
    gru_fused<2, 4><<<dim3(64, 4), 256, 0, stream>>>(
        ls0ob, ls1ib, ls1i, WihL1, WhhL1, wbfW, bih_l + 3072, bhh_l + 3072,
        ls1o, ls1ob, nullptr);
    ln_kernel<<<128, 256, 0, stream>>>(ls1o, ln_g, ln_b, Ybf, w);
  }

  // ---- final projection: (2048 x 1024) @ Wout^T -> (2048 x 32000) ----
  gemm2<4, 4, 1><<<dim3(500, 32), 64, 0, stream>>>(
      Ybf, 1024, packWout ? (const void*)WoutB : (const void*)Wout, 1024, 0,
      packWout ? 1 : 0, nullptr, 0, out, nullptr, 32000, 1024);
}

// Round 3
// 1386.260 us; speedup vs baseline: 8.3031x; 1.5469x over previous
//
#include <hip/hip_runtime.h>

typedef unsigned short u16;
typedef float f32x4 __attribute__((ext_vector_type(4)));
typedef __bf16 bf16x8 __attribute__((ext_vector_type(8)));
typedef u16 u16x8 __attribute__((ext_vector_type(8)));

#define DEVFN __device__ __forceinline__

// B=8, S=256, V=32000, H=1024, HEADS=8, HD=128, N_HIGH=4, N_LOW=16, RATIO=4
// Block = 16 timesteps; 16 blocks. Row layout R(t,b) = (w*16 + o*4 + g)*8 + b,
// w=t/16, g=(t%16)/4, o=t%4. High rows = first 32 of each 128-row block.
// States are stored per block-index: state[k] = state after processing block k-1
// (state[0] = zeros). This makes the dual-GRU pairing race-free.

DEVFN u16 f2bf(float f) {
  unsigned u = __builtin_bit_cast(unsigned, f);
  unsigned r = u + 0x7FFFu + ((u >> 16) & 1u);   // RNE
  return (u16)(r >> 16);
}

DEVFN bf16x8 cvt8(const float* p) {
  float4 f0 = *reinterpret_cast<const float4*>(p);
  float4 f1 = *reinterpret_cast<const float4*>(p + 4);
  u16x8 u;
  u[0] = f2bf(f0.x); u[1] = f2bf(f0.y); u[2] = f2bf(f0.z); u[3] = f2bf(f0.w);
  u[4] = f2bf(f1.x); u[5] = f2bf(f1.y); u[6] = f2bf(f1.z); u[7] = f2bf(f1.w);
  return __builtin_bit_cast(bf16x8, u);
}

DEVFN bf16x8 ldbf(const u16* p) { return *reinterpret_cast<const bf16x8*>(p); }
DEVFN float sigm(float x) { return 1.f / (1.f + expf(-x)); }

// ---------------- generic GEMM: OUT[M][N] = A[M][K](bf16) @ W[N][K]^T (+Cadd) --------
template<int MT, int NT, int KW>
__global__ __launch_bounds__(64 * KW) void gemm2(
    const u16* __restrict__ A, int lda,
    const void* __restrict__ Wp, int ldw, int kwoff, int wbf,
    const float* __restrict__ Cadd, int ldc,
    float* __restrict__ OUT, u16* __restrict__ OUTbf, int ldo, int K) {
  int tid = threadIdx.x;
  int kw = tid >> 6;
  int lane = tid & 63;
  int lr = lane & 15;
  int kk = (lane >> 4) << 3;
  int n0 = blockIdx.x * (16 * NT);
  int m0 = blockIdx.y * (16 * MT);
  int KP = K / KW;
  int kb = kw * KP + kk;

  f32x4 acc[MT][NT];
#pragma unroll
  for (int mi = 0; mi < MT; ++mi)
#pragma unroll
    for (int ni = 0; ni < NT; ++ni) acc[mi][ni] = f32x4{0.f, 0.f, 0.f, 0.f};

  const u16* ap[MT];
#pragma unroll
  for (int mi = 0; mi < MT; ++mi) ap[mi] = A + (size_t)(m0 + mi * 16 + lr) * (size_t)lda + kb;

  if (wbf) {
    const u16* wb[NT];
#pragma unroll
    for (int ni = 0; ni < NT; ++ni)
      wb[ni] = (const u16*)Wp + (size_t)(n0 + ni * 16 + lr) * (size_t)ldw + kwoff + kb;
    for (int k0 = 0; k0 < KP; k0 += 32) {
      bf16x8 wv[NT];
#pragma unroll
      for (int ni = 0; ni < NT; ++ni) wv[ni] = ldbf(wb[ni] + k0);
#pragma unroll
      for (int mi = 0; mi < MT; ++mi) {
        bf16x8 a = ldbf(ap[mi] + k0);
#pragma unroll
        for (int ni = 0; ni < NT; ++ni)
          acc[mi][ni] = __builtin_amdgcn_mfma_f32_16x16x32_bf16(a, wv[ni], acc[mi][ni], 0, 0, 0);
      }
    }
  } else {
    const float* wf[NT];
#pragma unroll
    for (int ni = 0; ni < NT; ++ni)
      wf[ni] = (const float*)Wp + (size_t)(n0 + ni * 16 + lr) * (size_t)ldw + kwoff + kb;
    for (int k0 = 0; k0 < KP; k0 += 32) {
      bf16x8 wv[NT];
#pragma unroll
      for (int ni = 0; ni < NT; ++ni) wv[ni] = cvt8(wf[ni] + k0);
#pragma unroll
      for (int mi = 0; mi < MT; ++mi) {
        bf16x8 a = ldbf(ap[mi] + k0);
#pragma unroll
        for (int ni = 0; ni < NT; ++ni)
          acc[mi][ni] = __builtin_amdgcn_mfma_f32_16x16x32_bf16(a, wv[ni], acc[mi][ni], 0, 0, 0);
      }
    }
  }

  if constexpr (KW > 1) {
    __shared__ f32x4 red[KW][MT * NT][64];
#pragma unroll
    for (int mi = 0; mi < MT; ++mi)
#pragma unroll
      for (int ni = 0; ni < NT; ++ni) red[kw][mi * NT + ni][lane] = acc[mi][ni];
    __syncthreads();
    if (kw) return;
    for (int w2 = 1; w2 < KW; ++w2)
#pragma unroll
      for (int mi = 0; mi < MT; ++mi)
#pragma unroll
        for (int ni = 0; ni < NT; ++ni) acc[mi][ni] += red[w2][mi * NT + ni][lane];
  }

  int rb = (lane >> 4) << 2;
#pragma unroll
  for (int mi = 0; mi < MT; ++mi)
#pragma unroll
    for (int ni = 0; ni < NT; ++ni)
#pragma unroll
      for (int rr = 0; rr < 4; ++rr) {
        int row = m0 + mi * 16 + rb + rr;
        int col = n0 + ni * 16 + lr;
        size_t o = (size_t)row * (size_t)ldo + col;
        float v = acc[mi][ni][rr];
        if (Cadd) v += Cadd[(size_t)row * (size_t)ldc + col];
        if (OUT) OUT[o] = v;
        if (OUTbf) OUTbf[o] = f2bf(v);
      }
}

// ---------------- dual-problem fused GRU layer (two independent GRU evals) ----------
struct GruP {
  const u16* X; const u16* Hb; const float* Hf;
  const u16* Wbih; const u16* Wbhh;
  const float* Wfih; const float* Wfhh;
  const float* bih; const float* bhh;
  float* Hof; u16* Hob; u16* hist;
};

__global__ __launch_bounds__(256) void gru_dual(GruP pa, GruP pb, int tiles1, int wbf) {
  GruP p; int m0;
  if ((int)blockIdx.y < tiles1) { p = pa; m0 = blockIdx.y * 32; }
  else { p = pb; m0 = ((int)blockIdx.y - tiles1) * 32; }
  int tid = threadIdx.x;
  int kw = tid >> 6;          // 4-way K split
  int lane = tid & 63;
  int lr = lane & 15;
  int kk = (lane >> 4) << 3;
  int j0 = blockIdx.x * 16;
  const int KP = 256;
  int kb = kw * KP + kk;

  f32x4 aR[2], aZ[2], aNX[2], aNH[2];
#pragma unroll
  for (int mi = 0; mi < 2; ++mi) {
    aR[mi] = f32x4{0.f, 0.f, 0.f, 0.f};
    aZ[mi] = f32x4{0.f, 0.f, 0.f, 0.f};
    aNX[mi] = f32x4{0.f, 0.f, 0.f, 0.f};
    aNH[mi] = f32x4{0.f, 0.f, 0.f, 0.f};
  }

  const u16* xp[2];
  const u16* hp[2];
#pragma unroll
  for (int mi = 0; mi < 2; ++mi) {
    size_t ro = (size_t)(m0 + mi * 16 + lr) * 1024 + kb;
    xp[mi] = p.X + ro;
    hp[mi] = p.Hb + ro;
  }

  size_t wro = (size_t)(j0 + lr) * 1024 + kb;
  if (wbf) {
    const u16 *pxr = p.Wbih + wro, *pxz = p.Wbih + wro + 1048576, *pxn = p.Wbih + wro + 2097152;
    const u16 *phr = p.Wbhh + wro, *phz = p.Wbhh + wro + 1048576, *phn = p.Wbhh + wro + 2097152;
    for (int k0 = 0; k0 < KP; k0 += 32) {
      bf16x8 wxr = ldbf(pxr + k0), wxz = ldbf(pxz + k0), wxn = ldbf(pxn + k0);
      bf16x8 whr = ldbf(phr + k0), whz = ldbf(phz + k0), whn = ldbf(phn + k0);
#pragma unroll
      for (int mi = 0; mi < 2; ++mi) {
        bf16x8 ax = ldbf(xp[mi] + k0);
        bf16x8 ah = ldbf(hp[mi] + k0);
        aR[mi] = __builtin_amdgcn_mfma_f32_16x16x32_bf16(ax, wxr, aR[mi], 0, 0, 0);
        aR[mi] = __builtin_amdgcn_mfma_f32_16x16x32_bf16(ah, whr, aR[mi], 0, 0, 0);
        aZ[mi] = __builtin_amdgcn_mfma_f32_16x16x32_bf16(ax, wxz, aZ[mi], 0, 0, 0);
        aZ[mi] = __builtin_amdgcn_mfma_f32_16x16x32_bf16(ah, whz, aZ[mi], 0, 0, 0);
        aNX[mi] = __builtin_amdgcn_mfma_f32_16x16x32_bf16(ax, wxn, aNX[mi], 0, 0, 0);
        aNH[mi] = __builtin_amdgcn_mfma_f32_16x16x32_bf16(ah, whn, aNH[mi], 0, 0, 0);
      }
    }
  } else {
    const float *pxr = p.Wfih + wro, *pxz = p.Wfih + wro + 1048576, *pxn = p.Wfih + wro + 2097152;
    const float *phr = p.Wfhh + wro, *phz = p.Wfhh + wro + 1048576, *phn = p.Wfhh + wro + 2097152;
    for (int k0 = 0; k0 < KP; k0 += 32) {
      bf16x8 wxr = cvt8(pxr + k0), wxz = cvt8(pxz + k0), wxn = cvt8(pxn + k0);
      bf16x8 whr = cvt8(phr + k0), whz = cvt8(phz + k0), whn = cvt8(phn + k0);
#pragma unroll
      for (int mi = 0; mi < 2; ++mi) {
        bf16x8 ax = ldbf(xp[mi] + k0);
        bf16x8 ah = ldbf(hp[mi] + k0);
        aR[mi] = __builtin_amdgcn_mfma_f32_16x16x32_bf16(ax, wxr, aR[mi], 0, 0, 0);
        aR[mi] = __builtin_amdgcn_mfma_f32_16x16x32_bf16(ah, whr, aR[mi], 0, 0, 0);
        aZ[mi] = __builtin_amdgcn_mfma_f32_16x16x32_bf16(ax, wxz, aZ[mi], 0, 0, 0);
        aZ[mi] = __builtin_amdgcn_mfma_f32_16x16x32_bf16(ah, whz, aZ[mi], 0, 0, 0);
        aNX[mi] = __builtin_amdgcn_mfma_f32_16x16x32_bf16(ax, wxn, aNX[mi], 0, 0, 0);
        aNH[mi] = __builtin_amdgcn_mfma_f32_16x16x32_bf16(ah, whn, aNH[mi], 0, 0, 0);
      }
    }
  }

  {
    __shared__ f32x4 red[4][8][64];
#pragma unroll
    for (int mi = 0; mi < 2; ++mi) {
      red[kw][mi * 4 + 0][lane] = aR[mi];
      red[kw][mi * 4 + 1][lane] = aZ[mi];
      red[kw][mi * 4 + 2][lane] = aNX[mi];
      red[kw][mi * 4 + 3][lane] = aNH[mi];
    }
    __syncthreads();
    if (kw) return;
    for (int w2 = 1; w2 < 4; ++w2)
#pragma unroll
      for (int mi = 0; mi < 2; ++mi) {
        aR[mi] += red[w2][mi * 4 + 0][lane];
        aZ[mi] += red[w2][mi * 4 + 1][lane];
        aNX[mi] += red[w2][mi * 4 + 2][lane];
        aNH[mi] += red[w2][mi * 4 + 3][lane];
      }
  }

  int c = j0 + lr;
  float br = p.bih[c] + p.bhh[c];
  float bz = p.bih[1024 + c] + p.bhh[1024 + c];
  float bnx = p.bih[2048 + c];
  float bnh = p.bhh[2048 + c];
  int rb = (lane >> 4) << 2;
#pragma unroll
  for (int mi = 0; mi < 2; ++mi)
#pragma unroll
    for (int rr = 0; rr < 4; ++rr) {
      int row = m0 + mi * 16 + rb + rr;
      float r = sigm(aR[mi][rr] + br);
      float z = sigm(aZ[mi][rr] + bz);
      float n = tanhf(aNX[mi][rr] + bnx + r * (aNH[mi][rr] + bnh));
      size_t o = (size_t)row * 1024 + c;
      float hv = (1.f - z) * n + z * p.Hf[o];
      p.Hof[o] = hv;
      u16 hb = f2bf(hv);
      p.Hob[o] = hb;
      if (p.hist) p.hist[o] = hb;
    }
}

// ---------------- final projection: 256x64 block tile, 4 waves, NT stores -----------
__global__ __launch_bounds__(256) void gemm_big(const u16* __restrict__ A,
                                                const void* __restrict__ Wp, int wbf,
                                                float* __restrict__ OUT) {
  int wv = threadIdx.x >> 6;
  int lane = threadIdx.x & 63;
  int lr = lane & 15;
  int kk = (lane >> 4) << 3;
  int m0 = blockIdx.x * 256 + wv * 64;
  int n0 = blockIdx.y * 64;

  f32x4 acc[4][4];
#pragma unroll
  for (int mi = 0; mi < 4; ++mi)
#pragma unroll
    for (int ni = 0; ni < 4; ++ni) acc[mi][ni] = f32x4{0.f, 0.f, 0.f, 0.f};

  const u16* ap[4];
#pragma unroll
  for (int mi = 0; mi < 4; ++mi) ap[mi] = A + (size_t)(m0 + mi * 16 + lr) * 1024 + kk;

  if (wbf) {
    const u16* wb[4];
#pragma unroll
    for (int ni = 0; ni < 4; ++ni) wb[ni] = (const u16*)Wp + (size_t)(n0 + ni * 16 + lr) * 1024 + kk;
    for (int k0 = 0; k0 < 1024; k0 += 32) {
      bf16x8 wvv[4];
#pragma unroll
      for (int ni = 0; ni < 4; ++ni) wvv[ni] = ldbf(wb[ni] + k0);
#pragma unroll
      for (int mi = 0; mi < 4; ++mi) {
        bf16x8 a = ldbf(ap[mi] + k0);
#pragma unroll
        for (int ni = 0; ni < 4; ++ni)
          acc[mi][ni] = __builtin_amdgcn_mfma_f32_16x16x32_bf16(a, wvv[ni], acc[mi][ni], 0, 0, 0);
      }
    }
  } else {
    const float* wf[4];
#pragma unroll
    for (int ni = 0; ni < 4; ++ni) wf[ni] = (const float*)Wp + (size_t)(n0 + ni * 16 + lr) * 1024 + kk;
    for (int k0 = 0; k0 < 1024; k0 += 32) {
      bf16x8 wvv[4];
#pragma unroll
      for (int ni = 0; ni < 4; ++ni) wvv[ni] = cvt8(wf[ni] + k0);
#pragma unroll
      for (int mi = 0; mi < 4; ++mi) {
        bf16x8 a = ldbf(ap[mi] + k0);
#pragma unroll
        for (int ni = 0; ni < 4; ++ni)
          acc[mi][ni] = __builtin_amdgcn_mfma_f32_16x16x32_bf16(a, wvv[ni], acc[mi][ni], 0, 0, 0);
      }
    }
  }

  int rb = (lane >> 4) << 2;
#pragma unroll
  for (int mi = 0; mi < 4; ++mi)
#pragma unroll
    for (int ni = 0; ni < 4; ++ni)
#pragma unroll
      for (int rr = 0; rr < 4; ++rr) {
        size_t o = (size_t)(m0 + mi * 16 + rb + rr) * 32000 + (size_t)(n0 + ni * 16 + lr);
        __builtin_nontemporal_store(acc[mi][ni][rr], &OUT[o]);
      }
}

// ---------------- weight fp32 -> bf16 pack ------------------------------------------
__global__ void cvt_w(const float* __restrict__ src, int src_ld, int col_off,
                      u16* __restrict__ dst, int log2c) {
  size_t idx = ((size_t)blockIdx.x * 256 + threadIdx.x) * 8;
  size_t row = idx >> log2c;
  int col = (int)(idx & ((1u << log2c) - 1));
  const float* s = src + row * (size_t)src_ld + col_off + col;
  *reinterpret_cast<u16x8*>(dst + idx) = __builtin_bit_cast(u16x8, cvt8(s));
}

// ---------------- embeds (bf16) -----------------------------------------------------
__global__ void embed_kernel(const int* __restrict__ ids, const float* __restrict__ emb,
                             const float* __restrict__ pos, u16* __restrict__ out) {
  int idx = blockIdx.x * 256 + threadIdx.x;
  int e8 = (idx & 127) << 3;
  int rb = idx >> 7;
  int t = rb >> 3, b = rb & 7;
  int w = t >> 4, lsp = t & 15, g = lsp >> 2, o = lsp & 3;
  int R = ((w << 4) + (o << 2) + g) * 8 + b;
  int tok = ids[b * 256 + t];
  const float* ep = emb + (size_t)tok * 1024 + e8;
  const float* pp = pos + (size_t)t * 1024 + e8;
  u16x8 u;
#pragma unroll
  for (int i = 0; i < 8; ++i) u[i] = f2bf(ep[i] + pp[i]);
  *reinterpret_cast<u16x8*>(out + (size_t)R * 1024 + e8) = u;
}

// ---------------- batched inp = gelu(einp + hc + bin) -------------------------------
__global__ void inp_all(const float* __restrict__ einp, const float* __restrict__ kvhAll,
                        const float* __restrict__ bin, float* __restrict__ inpb,
                        u16* __restrict__ inpbf) {
  int idx = blockIdx.x * 256 + threadIdx.x;   // 2048*1024
  int r = idx >> 10, j = idx & 1023;
  int w = r >> 7, r7 = r & 127;
  int g = (r7 >> 3) & 3, b = r7 & 7;
  float x = einp[idx] + kvhAll[(size_t)(w * 32 + g * 8 + b) * 3072 + 2048 + j] + bin[j];
  float t = tanhf(0.7978845608028654f * (x + 0.044715f * x * x * x));
  float v = 0.5f * x * (1.f + t);
  inpb[idx] = v;
  inpbf[idx] = f2bf(v);
}

// ---------------- batched attention -------------------------------------------------
__global__ void attn_all(const float* __restrict__ qb, const float* __restrict__ kvhAll,
                         u16* __restrict__ ctxbf) {
  int r = blockIdx.x;        // 0..2047
  int w = r >> 7, r7 = r & 127;
  int sp = r7 >> 3;
  int g = sp & 3;
  int b = r7 & 7;
  int lane = threadIdx.x;
  const float* kvb = kvhAll + (size_t)w * 32 * 3072;
  __shared__ float aw[8][4];
  if (lane < 32) {
    int head = lane >> 2, t = lane & 3;
    float s = 0.f;
    if (t <= g) {
      const float* qp = qb + (size_t)r * 1024 + head * 128;
      const float* kp = kvb + (size_t)(t * 8 + b) * 3072 + head * 128;
      for (int d = 0; d < 128; ++d) s += qp[d] * kp[d];
      s *= 0.08838834764831845f;
    }
    float sc[4];
    sc[0] = __shfl(s, (head << 2) + 0);
    sc[1] = __shfl(s, (head << 2) + 1);
    sc[2] = __shfl(s, (head << 2) + 2);
    sc[3] = __shfl(s, (head << 2) + 3);
    if (t == 0) {
      float mx = -1e30f;
      for (int u = 0; u <= g; ++u) mx = fmaxf(mx, sc[u]);
      float p[4] = {0.f, 0.f, 0.f, 0.f};
      float den = 0.f;
      for (int u = 0; u <= g; ++u) { p[u] = expf(sc[u] - mx); den += p[u]; }
      float inv = 1.f / den;
      for (int u = 0; u < 4; ++u) aw[head][u] = (u <= g) ? p[u] * inv : 0.f;
    }
  }
  __syncthreads();
  for (int idx = lane; idx < 1024; idx += 64) {
    int head = idx >> 7;
    float acc = 0.f;
#pragma unroll
    for (int t = 0; t < 4; ++t) acc += aw[head][t] * kvb[(size_t)(t * 8 + b) * 3072 + 1024 + idx];
    ctxbf[(size_t)r * 1024 + idx] = f2bf(acc);
  }
}

// ---------------- batched layernorm -> bf16 Y ---------------------------------------
__global__ void ln_all(const float* __restrict__ ls1f, const float* __restrict__ g_,
                       const float* __restrict__ b_, u16* __restrict__ Ybf) {
  int bid = blockIdx.x;      // 0..2047
  int w = bid >> 7, r7 = bid & 127;
  int tid = threadIdx.x;     // 256
  const float* x = ls1f + (size_t)(w + 1) * 131072 + (size_t)r7 * 1024;
  float s = 0.f, s2 = 0.f;
  for (int j = tid; j < 1024; j += 256) { float v = x[j]; s += v; s2 += v * v; }
  for (int off = 32; off; off >>= 1) { s += __shfl_xor(s, off); s2 += __shfl_xor(s2, off); }
  __shared__ float rs[4], rs2[4], mv[2];
  int wv = tid >> 6;
  if ((tid & 63) == 0) { rs[wv] = s; rs2[wv] = s2; }
  __syncthreads();
  if (tid == 0) {
    float S = rs[0] + rs[1] + rs[2] + rs[3];
    float S2 = rs2[0] + rs2[1] + rs2[2] + rs2[3];
    float mu = S * (1.f / 1024.f);
    float var = S2 * (1.f / 1024.f) - mu * mu;
    mv[0] = mu;
    mv[1] = rsqrtf(var + 1e-5f);
  }
  __syncthreads();
  float mu = mv[0], rstd = mv[1];
  int sp = r7 >> 3, b = r7 & 7;
  int g = sp & 3, o = sp >> 2;
  int t = w * 16 + g * 4 + o;
  u16* yrow = Ybf + (size_t)(b * 256 + t) * 1024;
  for (int j = tid; j < 1024; j += 256) {
    float v = (x[j] - mu) * rstd * g_[j] + b_[j];
    yrow[j] = f2bf(v);
  }
}

extern "C" void kernel_launch(void* const* d_in, const int* in_sizes, int n_in,
                              void* d_out, int out_size, void* d_ws, size_t ws_size,
                              hipStream_t stream) {
  const int* ids = (const int*)d_in[0];
  const float* emb = (const float*)d_in[1];
  const float* pos = (const float*)d_in[2];
  const float* Wih_h = (const float*)d_in[3];
  const float* bih_h = (const float*)d_in[4];
  const float* Whh_h = (const float*)d_in[5];
  const float* bhh_h = (const float*)d_in[6];
  const float* Win = (const float*)d_in[7];
  const float* bin_ = (const float*)d_in[8];
  const float* Wq = (const float*)d_in[9];
  const float* Wk = (const float*)d_in[10];
  const float* Wv = (const float*)d_in[11];
  const float* Wo = (const float*)d_in[12];
  const float* Wih_l = (const float*)d_in[13];
  const float* bih_l = (const float*)d_in[14];
  const float* Whh_l = (const float*)d_in[15];
  const float* bhh_l = (const float*)d_in[16];
  const float* ln_g = (const float*)d_in[17];
  const float* ln_b = (const float*)d_in[18];
  const float* Wout = (const float*)d_in[19];
  float* out = (float*)d_out;

  // ---- workspace bump allocator ----
  size_t off = 0;
  char* wsb = (char*)d_ws;
  auto allocF = [&](size_t n) { float* p = (float*)(wsb + off); off += n * 4; return p; };
  auto allocU = [&](size_t n) { u16* p = (u16*)(wsb + off); off += n * 2; return p; };

  // per-block-index state arrays [17]
  float* hs0f = allocF((size_t)17 * 32768);
  float* hs1f = allocF((size_t)17 * 32768);
  float* ls0f = allocF((size_t)17 * 131072);
  float* ls1f = allocF((size_t)17 * 131072);
  u16* hs0b = allocU((size_t)17 * 32768);
  u16* hs1b = allocU((size_t)17 * 32768);
  u16* ls0b = allocU((size_t)17 * 131072);
  u16* ls1b = allocU((size_t)17 * 131072);
  u16* histAll = allocU(524288);          // [16][32][1024]
  u16* embB = allocU(2097152);
  float* einp = allocF(2097152);
  float* kvhAll = allocF((size_t)512 * 3072);
  float* inpb = allocF(2097152);
  u16* inpbf = allocU(2097152);
  float* qb = allocF(2097152);
  u16* ctxbf = allocU(2097152);
  u16* x2bf = allocU(2097152);
  u16* Ybf = allocU(2097152);

  const size_t WPACK_BYTES = (size_t)(4 * 6291456 + 2097152 + 1048576 + 1048576 + 3145728) * 2;
  bool packW = (off + WPACK_BYTES <= ws_size);
  u16 *WihHb = nullptr, *WhhHb = nullptr, *WihLb = nullptr, *WhhLb = nullptr;
  u16 *WinB = nullptr, *WqB = nullptr, *WoB = nullptr, *KVp = nullptr;
  if (packW) {
    WihHb = allocU(6291456);
    WhhHb = allocU(6291456);
    WihLb = allocU(6291456);
    WhhLb = allocU(6291456);
    WinB = allocU(2097152);
    WqB = allocU(1048576);
    WoB = allocU(1048576);
    KVp = allocU(3145728);
  }
  bool packWout = packW && (off + (size_t)32768000 * 2 <= ws_size);
  u16* WoutB = nullptr;
  if (packWout) WoutB = allocU(32768000);

  // zero initial states (index 0 slices, fp32 + bf16)
  (void)hipMemsetAsync(hs0f, 0, 32768 * 4, stream);
  (void)hipMemsetAsync(hs1f, 0, 32768 * 4, stream);
  (void)hipMemsetAsync(ls0f, 0, 131072 * 4, stream);
  (void)hipMemsetAsync(ls1f, 0, 131072 * 4, stream);
  (void)hipMemsetAsync(hs0b, 0, 32768 * 2, stream);
  (void)hipMemsetAsync(hs1b, 0, 32768 * 2, stream);
  (void)hipMemsetAsync(ls0b, 0, 131072 * 2, stream);
  (void)hipMemsetAsync(ls1b, 0, 131072 * 2, stream);

  // ---- prologue ----
  embed_kernel<<<1024, 256, 0, stream>>>(ids, emb, pos, embB);
  if (packW) {
    cvt_w<<<3072, 256, 0, stream>>>(Wih_h, 1024, 0, WihHb, 10);
    cvt_w<<<3072, 256, 0, stream>>>(Whh_h, 1024, 0, WhhHb, 10);
    cvt_w<<<3072, 256, 0, stream>>>(Wih_l, 1024, 0, WihLb, 10);
    cvt_w<<<3072, 256, 0, stream>>>(Whh_l, 1024, 0, WhhLb, 10);
    cvt_w<<<1024, 256, 0, stream>>>(Win, 2048, 0, WinB, 11);
    cvt_w<<<512, 256, 0, stream>>>(Wq, 1024, 0, WqB, 10);
    cvt_w<<<512, 256, 0, stream>>>(Wo, 1024, 0, WoB, 10);
    cvt_w<<<512, 256, 0, stream>>>(Wk, 1024, 0, KVp, 10);
    cvt_w<<<512, 256, 0, stream>>>(Wv, 1024, 0, KVp + 1048576, 10);
    cvt_w<<<512, 256, 0, stream>>>(Win, 2048, 1024, KVp + 2097152, 10);
  }
  if (packWout) cvt_w<<<16000, 256, 0, stream>>>(Wout, 1024, 0, WoutB, 10);
  int wbfW = packW ? 1 : 0;

  // einp = embeds @ Win[:, :1024]^T (all 2048 rows)
  gemm2<2, 2, 2><<<dim3(32, 64), 128, 0, stream>>>(
      embB, 1024, packW ? (const void*)WinB : (const void*)Win, 2048, 0, wbfW,
      nullptr, 0, einp, nullptr, 1024, 1024);

  const size_t LW = (size_t)3072 * 1024;
  auto HP = [&](int layer, int w) {
    GruP p;
    if (layer == 0) {
      p.X = embB + (size_t)w * 131072;
      p.Hb = hs0b + (size_t)w * 32768; p.Hf = hs0f + (size_t)w * 32768;
      p.Wbih = WihHb; p.Wbhh = WhhHb; p.Wfih = Wih_h; p.Wfhh = Whh_h;
      p.bih = bih_h; p.bhh = bhh_h;
      p.Hof = hs0f + (size_t)(w + 1) * 32768; p.Hob = hs0b + (size_t)(w + 1) * 32768;
      p.hist = nullptr;
    } else {
      p.X = hs0b + (size_t)(w + 1) * 32768;
      p.Hb = hs1b + (size_t)w * 32768; p.Hf = hs1f + (size_t)w * 32768;
      p.Wbih = WihHb ? WihHb + LW : nullptr; p.Wbhh = WhhHb ? WhhHb + LW : nullptr;
      p.Wfih = Wih_h + LW; p.Wfhh = Whh_h + LW;
      p.bih = bih_h + 3072; p.bhh = bhh_h + 3072;
      p.Hof = hs1f + (size_t)(w + 1) * 32768; p.Hob = hs1b + (size_t)(w + 1) * 32768;
      p.hist = histAll + (size_t)w * 32768;
    }
    return p;
  };
  auto LP = [&](int layer, int w) {
    GruP p;
    if (layer == 0) {
      p.X = x2bf + (size_t)w * 131072;
      p.Hb = ls0b + (size_t)w * 131072; p.Hf = ls0f + (size_t)w * 131072;
      p.Wbih = WihLb; p.Wbhh = WhhLb; p.Wfih = Wih_l; p.Wfhh = Whh_l;
      p.bih = bih_l; p.bhh = bhh_l;
      p.Hof = ls0f + (size_t)(w + 1) * 131072; p.Hob = ls0b + (size_t)(w + 1) * 131072;
      p.hist = nullptr;
    } else {
      p.X = ls0b + (size_t)(w + 1) * 131072;
      p.Hb = ls1b + (size_t)w * 131072; p.Hf = ls1f + (size_t)w * 131072;
      p.Wbih = WihLb ? WihLb + LW : nullptr; p.Wbhh = WhhLb ? WhhLb + LW : nullptr;
      p.Wfih = Wih_l + LW; p.Wfhh = Whh_l + LW;
      p.bih = bih_l + 3072; p.bhh = bhh_l + 3072;
      p.Hof = ls1f + (size_t)(w + 1) * 131072; p.Hob = ls1b + (size_t)(w + 1) * 131072;
      p.hist = nullptr;
    }
    return p;
  };

  // ---- high chain: 17 dispatches (L1(w-1) paired with L0(w)) ----
  gru_dual<<<dim3(64, 1), 256, 0, stream>>>(HP(0, 0), HP(0, 0), 1, wbfW);
  for (int d = 1; d <= 15; ++d)
    gru_dual<<<dim3(64, 2), 256, 0, stream>>>(HP(1, d - 1), HP(0, d), 1, wbfW);
  gru_dual<<<dim3(64, 1), 256, 0, stream>>>(HP(1, 15), HP(1, 15), 1, wbfW);

  // ---- batched mid-section (all 16 blocks at once) ----
  if (packW) {
    gemm2<2, 2, 2><<<dim3(96, 16), 128, 0, stream>>>(
        histAll, 1024, KVp, 1024, 0, 1, nullptr, 0, kvhAll, nullptr, 3072, 1024);
  } else {
    gemm2<2, 2, 2><<<dim3(32, 16), 128, 0, stream>>>(
        histAll, 1024, Wk, 1024, 0, 0, nullptr, 0, kvhAll, nullptr, 3072, 1024);
    gemm2<2, 2, 2><<<dim3(32, 16), 128, 0, stream>>>(
        histAll, 1024, Wv, 1024, 0, 0, nullptr, 0, kvhAll + 1024, nullptr, 3072, 1024);
    gemm2<2, 2, 2><<<dim3(32, 16), 128, 0, stream>>>(
        histAll, 1024, Win, 2048, 1024, 0, nullptr, 0, kvhAll + 2048, nullptr, 3072, 1024);
  }
  inp_all<<<8192, 256, 0, stream>>>(einp, kvhAll, bin_, inpb, inpbf);
  gemm2<2, 2, 2><<<dim3(32, 64), 128, 0, stream>>>(
      inpbf, 1024, packW ? (const void*)WqB : (const void*)Wq, 1024, 0, wbfW,
      nullptr, 0, qb, nullptr, 1024, 1024);
  attn_all<<<2048, 64, 0, stream>>>(qb, kvhAll, ctxbf);
  gemm2<2, 2, 2><<<dim3(32, 64), 128, 0, stream>>>(
      ctxbf, 1024, packW ? (const void*)WoB : (const void*)Wo, 1024, 0, wbfW,
      inpb, 1024, nullptr, x2bf, 1024, 1024);

  // ---- low chain: 17 dispatches (l1(w-1) paired with l0(w)) ----
  gru_dual<<<dim3(64, 4), 256, 0, stream>>>(LP(0, 0), LP(0, 0), 4, wbfW);
  for (int d = 1; d <= 15; ++d)
    gru_dual<<<dim3(64, 8), 256, 0, stream>>>(LP(1, d - 1), LP(0, d), 4, wbfW);
  gru_dual<<<dim3(64, 4), 256, 0, stream>>>(LP(1, 15), LP(1, 15), 4, wbfW);

  // ---- layernorm (all blocks) + final projection ----
  ln_all<<<2048, 256, 0, stream>>>(ls1f, ln_g, ln_b, Ybf);
  gemm_big<<<dim3(8, 500), 256, 0, stream>>>(
      Ybf, packWout ? (const void*)WoutB : (const void*)Wout, packWout ? 1 : 0, out);
}

// Round 4
// 1108.572 us; speedup vs baseline: 10.3829x; 1.2505x over previous
//
#include <hip/hip_runtime.h>

typedef unsigned short u16;
typedef float f32x4 __attribute__((ext_vector_type(4)));
typedef __bf16 bf16x8 __attribute__((ext_vector_type(8)));
typedef u16 u16x8 __attribute__((ext_vector_type(8)));

#define DEVFN __device__ __forceinline__

// B=8, S=256, V=32000, H=1024, HEADS=8, HD=128, N_HIGH=4, N_LOW=16, RATIO=4
// Block = 16 timesteps; 16 blocks. Row layout R(t,b) = (w*16 + o*4 + g)*8 + b,
// w=t/16, g=(t%16)/4, o=t%4. High rows = first 32 of each 128-row block.
// States stored per block-index: state[k] = state after block k-1 (state[0]=0).

DEVFN u16 f2bf(float f) {
  unsigned u = __builtin_bit_cast(unsigned, f);
  unsigned r = u + 0x7FFFu + ((u >> 16) & 1u);   // RNE
  return (u16)(r >> 16);
}

DEVFN bf16x8 cvt8(const float* p) {
  float4 f0 = *reinterpret_cast<const float4*>(p);
  float4 f1 = *reinterpret_cast<const float4*>(p + 4);
  u16x8 u;
  u[0] = f2bf(f0.x); u[1] = f2bf(f0.y); u[2] = f2bf(f0.z); u[3] = f2bf(f0.w);
  u[4] = f2bf(f1.x); u[5] = f2bf(f1.y); u[6] = f2bf(f1.z); u[7] = f2bf(f1.w);
  return __builtin_bit_cast(bf16x8, u);
}

DEVFN bf16x8 ldbf(const u16* p) { return *reinterpret_cast<const bf16x8*>(p); }
DEVFN float sigm(float x) { return 1.f / (1.f + expf(-x)); }

DEVFN void gload16(const u16* g, u16* l) {
  __builtin_amdgcn_global_load_lds(
      (const __attribute__((address_space(1))) void*)g,
      (__attribute__((address_space(3))) void*)l, 16, 0, 0);
}

// ============ LDS-staged 128x128 GEMM, BK=32, 2-phase pipeline =====================
// OUT[M][N] = A[M][1024](bf16) @ W[N][1024](bf16)^T. 256 thr = 4 waves, each 64x64.
// XCD-bijective swizzle, M-fastest within chunk (W-panel stays in one XCD's L2).
template<int NTSTORE, int OUTF, int BF16OUT, int CADD>
__global__ __launch_bounds__(256) void gemm_lds(
    const u16* __restrict__ A, const u16* __restrict__ W,
    const float* __restrict__ Cadd,
    float* __restrict__ OUT, u16* __restrict__ OUTbf,
    int ldo, int mtiles) {
  __shared__ u16 smA[2][128 * 32];
  __shared__ u16 smB[2][128 * 32];

  int nwg = gridDim.x;
  int orig = blockIdx.x;
  int q = nwg >> 3, r = nwg & 7;
  int xcd = orig & 7, idx = orig >> 3;
  int wg = (xcd < r ? xcd * (q + 1) : r * (q + 1) + (xcd - r) * q) + idx;
  int m0 = (wg % mtiles) * 128;
  int n0 = (wg / mtiles) * 128;

  int tid = threadIdx.x;
  int wv = tid >> 6, lane = tid & 63;
  int lrow = lane >> 2;                      // 0..15
  int gcol = ((lane & 3) ^ (lrow & 3)) << 3; // 4-slot XOR swizzle (write side)

  const u16* gA0 = A + (size_t)(m0 + wv * 32 + lrow) * 1024 + gcol;
  const u16* gB0 = W + (size_t)(n0 + wv * 32 + lrow) * 1024 + gcol;
  u16* lA0 = &smA[0][(wv * 32) * 32];
  u16* lA1 = &smA[0][(wv * 32 + 16) * 32];
  u16* lB0 = &smB[0][(wv * 32) * 32];
  u16* lB1 = &smB[0][(wv * 32 + 16) * 32];
  const int BUFO = 128 * 32;                 // elems per buffer

  f32x4 acc[4][4];
#pragma unroll
  for (int mi = 0; mi < 4; ++mi)
#pragma unroll
    for (int ni = 0; ni < 4; ++ni) acc[mi][ni] = f32x4{0.f, 0.f, 0.f, 0.f};

  int qm = (wv >> 1) * 64, qn = (wv & 1) * 64;
  int lr = lane & 15;
  int kk = (lane >> 4) << 3;

  // stage(kt=0, buf=0)
  gload16(gA0, lA0);
  gload16(gA0 + 16 * 1024, lA1);
  gload16(gB0, lB0);
  gload16(gB0 + 16 * 1024, lB1);

  for (int kt = 0; kt < 32; ++kt) {
    int buf = kt & 1;
    __syncthreads();                         // drain vmcnt: stage(kt) ready
    if (kt < 31) {                           // issue stage(kt+1) into other buffer
      int k0 = (kt + 1) << 5;
      int bo = (buf ^ 1) * BUFO;
      gload16(gA0 + k0, lA0 + bo);
      gload16(gA0 + 16 * 1024 + k0, lA1 + bo);
      gload16(gB0 + k0, lB0 + bo);
      gload16(gB0 + 16 * 1024 + k0, lB1 + bo);
    }
    bf16x8 av[4], bv[4];
#pragma unroll
    for (int i = 0; i < 4; ++i) {
      int ra = qm + i * 16 + lr;
      av[i] = *(const bf16x8*)&smA[buf][ra * 32 + (kk ^ ((ra & 3) << 3))];
      int rbw = qn + i * 16 + lr;
      bv[i] = *(const bf16x8*)&smB[buf][rbw * 32 + (kk ^ ((rbw & 3) << 3))];
    }
#pragma unroll
    for (int mi = 0; mi < 4; ++mi)
#pragma unroll
      for (int ni = 0; ni < 4; ++ni)
        acc[mi][ni] = __builtin_amdgcn_mfma_f32_16x16x32_bf16(av[mi], bv[ni], acc[mi][ni], 0, 0, 0);
  }

  int rb = (lane >> 4) << 2;
#pragma unroll
  for (int mi = 0; mi < 4; ++mi)
#pragma unroll
    for (int ni = 0; ni < 4; ++ni)
#pragma unroll
      for (int rr = 0; rr < 4; ++rr) {
        int row = m0 + qm + mi * 16 + rb + rr;
        int col = n0 + qn + ni * 16 + lr;
        size_t o = (size_t)row * (size_t)ldo + col;
        float v = acc[mi][ni][rr];
        if constexpr (CADD) v += Cadd[o];
        if constexpr (OUTF) {
          if constexpr (NTSTORE) __builtin_nontemporal_store(v, &OUT[o]);
          else OUT[o] = v;
        }
        if constexpr (BF16OUT) OUTbf[o] = f2bf(v);
      }
}

// ---------------- generic GEMM (fallback, fp32-weight capable) ----------------------
template<int MT, int NT, int KW>
__global__ __launch_bounds__(64 * KW) void gemm2(
    const u16* __restrict__ A, int lda,
    const void* __restrict__ Wp, int ldw, int kwoff, int wbf,
    const float* __restrict__ Cadd, int ldc,
    float* __restrict__ OUT, u16* __restrict__ OUTbf, int ldo, int K) {
  int tid = threadIdx.x;
  int kw = tid >> 6;
  int lane = tid & 63;
  int lr = lane & 15;
  int kk = (lane >> 4) << 3;
  int n0 = blockIdx.x * (16 * NT);
  int m0 = blockIdx.y * (16 * MT);
  int KP = K / KW;
  int kb = kw * KP + kk;

  f32x4 acc[MT][NT];
#pragma unroll
  for (int mi = 0; mi < MT; ++mi)
#pragma unroll
    for (int ni = 0; ni < NT; ++ni) acc[mi][ni] = f32x4{0.f, 0.f, 0.f, 0.f};

  const u16* ap[MT];
#pragma unroll
  for (int mi = 0; mi < MT; ++mi) ap[mi] = A + (size_t)(m0 + mi * 16 + lr) * (size_t)lda + kb;

  if (wbf) {
    const u16* wb[NT];
#pragma unroll
    for (int ni = 0; ni < NT; ++ni)
      wb[ni] = (const u16*)Wp + (size_t)(n0 + ni * 16 + lr) * (size_t)ldw + kwoff + kb;
    for (int k0 = 0; k0 < KP; k0 += 32) {
      bf16x8 wv[NT];
#pragma unroll
      for (int ni = 0; ni < NT; ++ni) wv[ni] = ldbf(wb[ni] + k0);
#pragma unroll
      for (int mi = 0; mi < MT; ++mi) {
        bf16x8 a = ldbf(ap[mi] + k0);
#pragma unroll
        for (int ni = 0; ni < NT; ++ni)
          acc[mi][ni] = __builtin_amdgcn_mfma_f32_16x16x32_bf16(a, wv[ni], acc[mi][ni], 0, 0, 0);
      }
    }
  } else {
    const float* wf[NT];
#pragma unroll
    for (int ni = 0; ni < NT; ++ni)
      wf[ni] = (const float*)Wp + (size_t)(n0 + ni * 16 + lr) * (size_t)ldw + kwoff + kb;
    for (int k0 = 0; k0 < KP; k0 += 32) {
      bf16x8 wv[NT];
#pragma unroll
      for (int ni = 0; ni < NT; ++ni) wv[ni] = cvt8(wf[ni] + k0);
#pragma unroll
      for (int mi = 0; mi < MT; ++mi) {
        bf16x8 a = ldbf(ap[mi] + k0);
#pragma unroll
        for (int ni = 0; ni < NT; ++ni)
          acc[mi][ni] = __builtin_amdgcn_mfma_f32_16x16x32_bf16(a, wv[ni], acc[mi][ni], 0, 0, 0);
      }
    }
  }

  if constexpr (KW > 1) {
    __shared__ f32x4 red[KW][MT * NT][64];
#pragma unroll
    for (int mi = 0; mi < MT; ++mi)
#pragma unroll
      for (int ni = 0; ni < NT; ++ni) red[kw][mi * NT + ni][lane] = acc[mi][ni];
    __syncthreads();
    if (kw) return;
    for (int w2 = 1; w2 < KW; ++w2)
#pragma unroll
      for (int mi = 0; mi < MT; ++mi)
#pragma unroll
        for (int ni = 0; ni < NT; ++ni) acc[mi][ni] += red[w2][mi * NT + ni][lane];
  }

  int rb = (lane >> 4) << 2;
#pragma unroll
  for (int mi = 0; mi < MT; ++mi)
#pragma unroll
    for (int ni = 0; ni < NT; ++ni)
#pragma unroll
      for (int rr = 0; rr < 4; ++rr) {
        int row = m0 + mi * 16 + rb + rr;
        int col = n0 + ni * 16 + lr;
        size_t o = (size_t)row * (size_t)ldo + col;
        float v = acc[mi][ni][rr];
        if (Cadd) v += Cadd[(size_t)row * (size_t)ldc + col];
        if (OUT) OUT[o] = v;
        if (OUTbf) OUTbf[o] = f2bf(v);
      }
}

// ---------------- dual-problem fused GRU layer --------------------------------------
struct GruP {
  const u16* X; const u16* Hb; const float* Hf;
  const u16* Wbih; const u16* Wbhh;
  const float* Wfih; const float* Wfhh;
  const float* bih; const float* bhh;
  float* Hof; u16* Hob; u16* hist;
};

__global__ __launch_bounds__(256) void gru_dual(GruP pa, GruP pb, int tiles1, int wbf) {
  GruP p; int m0;
  if ((int)blockIdx.y < tiles1) { p = pa; m0 = blockIdx.y * 32; }
  else { p = pb; m0 = ((int)blockIdx.y - tiles1) * 32; }
  int tid = threadIdx.x;
  int kw = tid >> 6;
  int lane = tid & 63;
  int lr = lane & 15;
  int kk = (lane >> 4) << 3;
  int j0 = blockIdx.x * 16;
  const int KP = 256;
  int kb = kw * KP + kk;

  f32x4 aR[2], aZ[2], aNX[2], aNH[2];
#pragma unroll
  for (int mi = 0; mi < 2; ++mi) {
    aR[mi] = f32x4{0.f, 0.f, 0.f, 0.f};
    aZ[mi] = f32x4{0.f, 0.f, 0.f, 0.f};
    aNX[mi] = f32x4{0.f, 0.f, 0.f, 0.f};
    aNH[mi] = f32x4{0.f, 0.f, 0.f, 0.f};
  }

  const u16* xp[2];
  const u16* hp[2];
#pragma unroll
  for (int mi = 0; mi < 2; ++mi) {
    size_t ro = (size_t)(m0 + mi * 16 + lr) * 1024 + kb;
    xp[mi] = p.X + ro;
    hp[mi] = p.Hb + ro;
  }

  size_t wro = (size_t)(j0 + lr) * 1024 + kb;
  if (wbf) {
    const u16 *pxr = p.Wbih + wro, *pxz = p.Wbih + wro + 1048576, *pxn = p.Wbih + wro + 2097152;
    const u16 *phr = p.Wbhh + wro, *phz = p.Wbhh + wro + 1048576, *phn = p.Wbhh + wro + 2097152;
    for (int k0 = 0; k0 < KP; k0 += 32) {
      bf16x8 wxr = ldbf(pxr + k0), wxz = ldbf(pxz + k0), wxn = ldbf(pxn + k0);
      bf16x8 whr = ldbf(phr + k0), whz = ldbf(phz + k0), whn = ldbf(phn + k0);
#pragma unroll
      for (int mi = 0; mi < 2; ++mi) {
        bf16x8 ax = ldbf(xp[mi] + k0);
        bf16x8 ah = ldbf(hp[mi] + k0);
        aR[mi] = __builtin_amdgcn_mfma_f32_16x16x32_bf16(ax, wxr, aR[mi], 0, 0, 0);
        aR[mi] = __builtin_amdgcn_mfma_f32_16x16x32_bf16(ah, whr, aR[mi], 0, 0, 0);
        aZ[mi] = __builtin_amdgcn_mfma_f32_16x16x32_bf16(ax, wxz, aZ[mi], 0, 0, 0);
        aZ[mi] = __builtin_amdgcn_mfma_f32_16x16x32_bf16(ah, whz, aZ[mi], 0, 0, 0);
        aNX[mi] = __builtin_amdgcn_mfma_f32_16x16x32_bf16(ax, wxn, aNX[mi], 0, 0, 0);
        aNH[mi] = __builtin_amdgcn_mfma_f32_16x16x32_bf16(ah, whn, aNH[mi], 0, 0, 0);
      }
    }
  } else {
    const float *pxr = p.Wfih + wro, *pxz = p.Wfih + wro + 1048576, *pxn = p.Wfih + wro + 2097152;
    const float *phr = p.Wfhh + wro, *phz = p.Wfhh + wro + 1048576, *phn = p.Wfhh + wro + 2097152;
    for (int k0 = 0; k0 < KP; k0 += 32) {
      bf16x8 wxr = cvt8(pxr + k0), wxz = cvt8(pxz + k0), wxn = cvt8(pxn + k0);
      bf16x8 whr = cvt8(phr + k0), whz = cvt8(phz + k0), whn = cvt8(phn + k0);
#pragma unroll
      for (int mi = 0; mi < 2; ++mi) {
        bf16x8 ax = ldbf(xp[mi] + k0);
        bf16x8 ah = ldbf(hp[mi] + k0);
        aR[mi] = __builtin_amdgcn_mfma_f32_16x16x32_bf16(ax, wxr, aR[mi], 0, 0, 0);
        aR[mi] = __builtin_amdgcn_mfma_f32_16x16x32_bf16(ah, whr, aR[mi], 0, 0, 0);
        aZ[mi] = __builtin_amdgcn_mfma_f32_16x16x32_bf16(ax, wxz, aZ[mi], 0, 0, 0);
        aZ[mi] = __builtin_amdgcn_mfma_f32_16x16x32_bf16(ah, whz, aZ[mi], 0, 0, 0);
        aNX[mi] = __builtin_amdgcn_mfma_f32_16x16x32_bf16(ax, wxn, aNX[mi], 0, 0, 0);
        aNH[mi] = __builtin_amdgcn_mfma_f32_16x16x32_bf16(ah, whn, aNH[mi], 0, 0, 0);
      }
    }
  }

  {
    __shared__ f32x4 red[4][8][64];
#pragma unroll
    for (int mi = 0; mi < 2; ++mi) {
      red[kw][mi * 4 + 0][lane] = aR[mi];
      red[kw][mi * 4 + 1][lane] = aZ[mi];
      red[kw][mi * 4 + 2][lane] = aNX[mi];
      red[kw][mi * 4 + 3][lane] = aNH[mi];
    }
    __syncthreads();
    if (kw) return;
    for (int w2 = 1; w2 < 4; ++w2)
#pragma unroll
      for (int mi = 0; mi < 2; ++mi) {
        aR[mi] += red[w2][mi * 4 + 0][lane];
        aZ[mi] += red[w2][mi * 4 + 1][lane];
        aNX[mi] += red[w2][mi * 4 + 2][lane];
        aNH[mi] += red[w2][mi * 4 + 3][lane];
      }
  }

  int c = j0 + lr;
  float br = p.bih[c] + p.bhh[c];
  float bz = p.bih[1024 + c] + p.bhh[1024 + c];
  float bnx = p.bih[2048 + c];
  float bnh = p.bhh[2048 + c];
  int rb = (lane >> 4) << 2;
#pragma unroll
  for (int mi = 0; mi < 2; ++mi)
#pragma unroll
    for (int rr = 0; rr < 4; ++rr) {
      int row = m0 + mi * 16 + rb + rr;
      float r = sigm(aR[mi][rr] + br);
      float z = sigm(aZ[mi][rr] + bz);
      float n = tanhf(aNX[mi][rr] + bnx + r * (aNH[mi][rr] + bnh));
      size_t o = (size_t)row * 1024 + c;
      float hv = (1.f - z) * n + z * p.Hf[o];
      p.Hof[o] = hv;
      u16 hb = f2bf(hv);
      p.Hob[o] = hb;
      if (p.hist) p.hist[o] = hb;
    }
}

// ---------------- final projection fallback (fp32 W, direct) ------------------------
__global__ __launch_bounds__(256) void gemm_big(const u16* __restrict__ A,
                                                const void* __restrict__ Wp, int wbf,
                                                float* __restrict__ OUT) {
  int wv = threadIdx.x >> 6;
  int lane = threadIdx.x & 63;
  int lr = lane & 15;
  int kk = (lane >> 4) << 3;
  int m0 = blockIdx.x * 256 + wv * 64;
  int n0 = blockIdx.y * 64;

  f32x4 acc[4][4];
#pragma unroll
  for (int mi = 0; mi < 4; ++mi)
#pragma unroll
    for (int ni = 0; ni < 4; ++ni) acc[mi][ni] = f32x4{0.f, 0.f, 0.f, 0.f};

  const u16* ap[4];
#pragma unroll
  for (int mi = 0; mi < 4; ++mi) ap[mi] = A + (size_t)(m0 + mi * 16 + lr) * 1024 + kk;

  const float* wf[4];
#pragma unroll
  for (int ni = 0; ni < 4; ++ni) wf[ni] = (const float*)Wp + (size_t)(n0 + ni * 16 + lr) * 1024 + kk;
  for (int k0 = 0; k0 < 1024; k0 += 32) {
    bf16x8 wvv[4];
#pragma unroll
    for (int ni = 0; ni < 4; ++ni) wvv[ni] = cvt8(wf[ni] + k0);
#pragma unroll
    for (int mi = 0; mi < 4; ++mi) {
      bf16x8 a = ldbf(ap[mi] + k0);
#pragma unroll
      for (int ni = 0; ni < 4; ++ni)
        acc[mi][ni] = __builtin_amdgcn_mfma_f32_16x16x32_bf16(a, wvv[ni], acc[mi][ni], 0, 0, 0);
    }
  }

  int rb = (lane >> 4) << 2;
#pragma unroll
  for (int mi = 0; mi < 4; ++mi)
#pragma unroll
    for (int ni = 0; ni < 4; ++ni)
#pragma unroll
      for (int rr = 0; rr < 4; ++rr) {
        size_t o = (size_t)(m0 + mi * 16 + rb + rr) * 32000 + (size_t)(n0 + ni * 16 + lr);
        __builtin_nontemporal_store(acc[mi][ni][rr], &OUT[o]);
      }
}

// ---------------- weight fp32 -> bf16 pack ------------------------------------------
__global__ void cvt_w(const float* __restrict__ src, int src_ld, int col_off,
                      u16* __restrict__ dst, int log2c) {
  size_t idx = ((size_t)blockIdx.x * 256 + threadIdx.x) * 8;
  size_t row = idx >> log2c;
  int col = (int)(idx & ((1u << log2c) - 1));
  const float* s = src + row * (size_t)src_ld + col_off + col;
  *reinterpret_cast<u16x8*>(dst + idx) = __builtin_bit_cast(u16x8, cvt8(s));
}

// ---------------- embeds (bf16) -----------------------------------------------------
__global__ void embed_kernel(const int* __restrict__ ids, const float* __restrict__ emb,
                             const float* __restrict__ pos, u16* __restrict__ out) {
  int idx = blockIdx.x * 256 + threadIdx.x;
  int e8 = (idx & 127) << 3;
  int rb = idx >> 7;
  int t = rb >> 3, b = rb & 7;
  int w = t >> 4, lsp = t & 15, g = lsp >> 2, o = lsp & 3;
  int R = ((w << 4) + (o << 2) + g) * 8 + b;
  int tok = ids[b * 256 + t];
  const float* ep = emb + (size_t)tok * 1024 + e8;
  const float* pp = pos + (size_t)t * 1024 + e8;
  u16x8 u;
#pragma unroll
  for (int i = 0; i < 8; ++i) u[i] = f2bf(ep[i] + pp[i]);
  *reinterpret_cast<u16x8*>(out + (size_t)R * 1024 + e8) = u;
}

// ---------------- batched inp = gelu(einp + hc + bin) -------------------------------
__global__ void inp_all(const float* __restrict__ einp, const float* __restrict__ kvhAll,
                        const float* __restrict__ bin, float* __restrict__ inpb,
                        u16* __restrict__ inpbf) {
  int idx = blockIdx.x * 256 + threadIdx.x;   // 2048*1024
  int r = idx >> 10, j = idx & 1023;
  int w = r >> 7, r7 = r & 127;
  int g = (r7 >> 3) & 3, b = r7 & 7;
  float x = einp[idx] + kvhAll[(size_t)(w * 32 + g * 8 + b) * 3072 + 2048 + j] + bin[j];
  float t = tanhf(0.7978845608028654f * (x + 0.044715f * x * x * x));
  float v = 0.5f * x * (1.f + t);
  inpb[idx] = v;
  inpbf[idx] = f2bf(v);
}

// ---------------- batched attention -------------------------------------------------
__global__ void attn_all(const float* __restrict__ qb, const float* __restrict__ kvhAll,
                         u16* __restrict__ ctxbf) {
  int r = blockIdx.x;        // 0..2047
  int w = r >> 7, r7 = r & 127;
  int sp = r7 >> 3;
  int g = sp & 3;
  int b = r7 & 7;
  int lane = threadIdx.x;
  const float* kvb = kvhAll + (size_t)w * 32 * 3072;
  __shared__ float aw[8][4];
  if (lane < 32) {
    int head = lane >> 2, t = lane & 3;
    float s = 0.f;
    if (t <= g) {
      const float* qp = qb + (size_t)r * 1024 + head * 128;
      const float* kp = kvb + (size_t)(t * 8 + b) * 3072 + head * 128;
      for (int d = 0; d < 128; ++d) s += qp[d] * kp[d];
      s *= 0.08838834764831845f;
    }
    float sc[4];
    sc[0] = __shfl(s, (head << 2) + 0);
    sc[1] = __shfl(s, (head << 2) + 1);
    sc[2] = __shfl(s, (head << 2) + 2);
    sc[3] = __shfl(s, (head << 2) + 3);
    if (t == 0) {
      float mx = -1e30f;
      for (int u = 0; u <= g; ++u) mx = fmaxf(mx, sc[u]);
      float p[4] = {0.f, 0.f, 0.f, 0.f};
      float den = 0.f;
      for (int u = 0; u <= g; ++u) { p[u] = expf(sc[u] - mx); den += p[u]; }
      float inv = 1.f / den;
      for (int u = 0; u < 4; ++u) aw[head][u] = (u <= g) ? p[u] * inv : 0.f;
    }
  }
  __syncthreads();
  for (int idx = lane; idx < 1024; idx += 64) {
    int head = idx >> 7;
    float acc = 0.f;
#pragma unroll
    for (int t = 0; t < 4; ++t) acc += aw[head][t] * kvb[(size_t)(t * 8 + b) * 3072 + 1024 + idx];
    ctxbf[(size_t)r * 1024 + idx] = f2bf(acc);
  }
}

// ---------------- batched layernorm -> bf16 Y ---------------------------------------
__global__ void ln_all(const float* __restrict__ ls1f, const float* __restrict__ g_,
                       const float* __restrict__ b_, u16* __restrict__ Ybf) {
  int bid = blockIdx.x;      // 0..2047
  int w = bid >> 7, r7 = bid & 127;
  int tid = threadIdx.x;     // 256
  const float* x = ls1f + (size_t)(w + 1) * 131072 + (size_t)r7 * 1024;
  float s = 0.f, s2 = 0.f;
  for (int j = tid; j < 1024; j += 256) { float v = x[j]; s += v; s2 += v * v; }
  for (int off = 32; off; off >>= 1) { s += __shfl_xor(s, off); s2 += __shfl_xor(s2, off); }
  __shared__ float rs[4], rs2[4], mv[2];
  int wv = tid >> 6;
  if ((tid & 63) == 0) { rs[wv] = s; rs2[wv] = s2; }
  __syncthreads();
  if (tid == 0) {
    float S = rs[0] + rs[1] + rs[2] + rs[3];
    float S2 = rs2[0] + rs2[1] + rs2[2] + rs2[3];
    float mu = S * (1.f / 1024.f);
    float var = S2 * (1.f / 1024.f) - mu * mu;
    mv[0] = mu;
    mv[1] = rsqrtf(var + 1e-5f);
  }
  __syncthreads();
  float mu = mv[0], rstd = mv[1];
  int sp = r7 >> 3, b = r7 & 7;
  int g = sp & 3, o = sp >> 2;
  int t = w * 16 + g * 4 + o;
  u16* yrow = Ybf + (size_t)(b * 256 + t) * 1024;
  for (int j = tid; j < 1024; j += 256) {
    float v = (x[j] - mu) * rstd * g_[j] + b_[j];
    yrow[j] = f2bf(v);
  }
}

extern "C" void kernel_launch(void* const* d_in, const int* in_sizes, int n_in,
                              void* d_out, int out_size, void* d_ws, size_t ws_size,
                              hipStream_t stream) {
  const int* ids = (const int*)d_in[0];
  const float* emb = (const float*)d_in[1];
  const float* pos = (const float*)d_in[2];
  const float* Wih_h = (const float*)d_in[3];
  const float* bih_h = (const float*)d_in[4];
  const float* Whh_h = (const float*)d_in[5];
  const float* bhh_h = (const float*)d_in[6];
  const float* Win = (const float*)d_in[7];
  const float* bin_ = (const float*)d_in[8];
  const float* Wq = (const float*)d_in[9];
  const float* Wk = (const float*)d_in[10];
  const float* Wv = (const float*)d_in[11];
  const float* Wo = (const float*)d_in[12];
  const float* Wih_l = (const float*)d_in[13];
  const float* bih_l = (const float*)d_in[14];
  const float* Whh_l = (const float*)d_in[15];
  const float* bhh_l = (const float*)d_in[16];
  const float* ln_g = (const float*)d_in[17];
  const float* ln_b = (const float*)d_in[18];
  const float* Wout = (const float*)d_in[19];
  float* out = (float*)d_out;

  // ---- workspace bump allocator ----
  size_t off = 0;
  char* wsb = (char*)d_ws;
  auto allocF = [&](size_t n) { float* p = (float*)(wsb + off); off += n * 4; return p; };
  auto allocU = [&](size_t n) { u16* p = (u16*)(wsb + off); off += n * 2; return p; };

  // per-block-index state arrays [17]
  float* hs0f = allocF((size_t)17 * 32768);
  float* hs1f = allocF((size_t)17 * 32768);
  float* ls0f = allocF((size_t)17 * 131072);
  float* ls1f = allocF((size_t)17 * 131072);
  u16* hs0b = allocU((size_t)17 * 32768);
  u16* hs1b = allocU((size_t)17 * 32768);
  u16* ls0b = allocU((size_t)17 * 131072);
  u16* ls1b = allocU((size_t)17 * 131072);
  u16* histAll = allocU(524288);          // [16][32][1024]
  u16* embB = allocU(2097152);
  float* einp = allocF(2097152);
  float* kvhAll = allocF((size_t)512 * 3072);
  float* inpb = allocF(2097152);
  u16* inpbf = allocU(2097152);
  float* qb = allocF(2097152);
  u16* ctxbf = allocU(2097152);
  u16* x2bf = allocU(2097152);
  u16* Ybf = allocU(2097152);

  const size_t WPACK_BYTES = (size_t)(4 * 6291456 + 1048576 + 1048576 + 1048576 + 3145728) * 2;
  bool packW = (off + WPACK_BYTES <= ws_size);
  u16 *WihHb = nullptr, *WhhHb = nullptr, *WihLb = nullptr, *WhhLb = nullptr;
  u16 *WinB0 = nullptr, *WqB = nullptr, *WoB = nullptr, *KVp = nullptr;
  if (packW) {
    WihHb = allocU(6291456);
    WhhHb = allocU(6291456);
    WihLb = allocU(6291456);
    WhhLb = allocU(6291456);
    WinB0 = allocU(1048576);   // Win[:, :1024] as [1024][1024]
    WqB = allocU(1048576);
    WoB = allocU(1048576);
    KVp = allocU(3145728);     // Wk | Wv | Win[:, 1024:]
  }
  bool packWout = packW && (off + (size_t)32768000 * 2 <= ws_size);
  u16* WoutB = nullptr;
  if (packWout) WoutB = allocU(32768000);

  // zero initial states (index 0 slices, fp32 + bf16)
  (void)hipMemsetAsync(hs0f, 0, 32768 * 4, stream);
  (void)hipMemsetAsync(hs1f, 0, 32768 * 4, stream);
  (void)hipMemsetAsync(ls0f, 0, 131072 * 4, stream);
  (void)hipMemsetAsync(ls1f, 0, 131072 * 4, stream);
  (void)hipMemsetAsync(hs0b, 0, 32768 * 2, stream);
  (void)hipMemsetAsync(hs1b, 0, 32768 * 2, stream);
  (void)hipMemsetAsync(ls0b, 0, 131072 * 2, stream);
  (void)hipMemsetAsync(ls1b, 0, 131072 * 2, stream);

  // ---- prologue ----
  embed_kernel<<<1024, 256, 0, stream>>>(ids, emb, pos, embB);
  if (packW) {
    cvt_w<<<3072, 256, 0, stream>>>(Wih_h, 1024, 0, WihHb, 10);
    cvt_w<<<3072, 256, 0, stream>>>(Whh_h, 1024, 0, WhhHb, 10);
    cvt_w<<<3072, 256, 0, stream>>>(Wih_l, 1024, 0, WihLb, 10);
    cvt_w<<<3072, 256, 0, stream>>>(Whh_l, 1024, 0, WhhLb, 10);
    cvt_w<<<512, 256, 0, stream>>>(Win, 2048, 0, WinB0, 10);
    cvt_w<<<512, 256, 0, stream>>>(Wq, 1024, 0, WqB, 10);
    cvt_w<<<512, 256, 0, stream>>>(Wo, 1024, 0, WoB, 10);
    cvt_w<<<512, 256, 0, stream>>>(Wk, 1024, 0, KVp, 10);
    cvt_w<<<512, 256, 0, stream>>>(Wv, 1024, 0, KVp + 1048576, 10);
    cvt_w<<<512, 256, 0, stream>>>(Win, 2048, 1024, KVp + 2097152, 10);
  }
  if (packWout) cvt_w<<<16000, 256, 0, stream>>>(Wout, 1024, 0, WoutB, 10);
  int wbfW = packW ? 1 : 0;

  // einp = embeds @ Win[:, :1024]^T (all 2048 rows)
  if (packW)
    gemm_lds<0, 1, 0, 0><<<128, 256, 0, stream>>>(embB, WinB0, nullptr, einp, nullptr, 1024, 16);
  else
    gemm2<2, 2, 2><<<dim3(32, 64), 128, 0, stream>>>(
        embB, 1024, Win, 2048, 0, 0, nullptr, 0, einp, nullptr, 1024, 1024);

  const size_t LW = (size_t)3072 * 1024;
  auto HP = [&](int layer, int w) {
    GruP p;
    if (layer == 0) {
      p.X = embB + (size_t)w * 131072;
      p.Hb = hs0b + (size_t)w * 32768; p.Hf = hs0f + (size_t)w * 32768;
      p.Wbih = WihHb; p.Wbhh = WhhHb; p.Wfih = Wih_h; p.Wfhh = Whh_h;
      p.bih = bih_h; p.bhh = bhh_h;
      p.Hof = hs0f + (size_t)(w + 1) * 32768; p.Hob = hs0b + (size_t)(w + 1) * 32768;
      p.hist = nullptr;
    } else {
      p.X = hs0b + (size_t)(w + 1) * 32768;
      p.Hb = hs1b + (size_t)w * 32768; p.Hf = hs1f + (size_t)w * 32768;
      p.Wbih = WihHb ? WihHb + LW : nullptr; p.Wbhh = WhhHb ? WhhHb + LW : nullptr;
      p.Wfih = Wih_h + LW; p.Wfhh = Whh_h + LW;
      p.bih = bih_h + 3072; p.bhh = bhh_h + 3072;
      p.Hof = hs1f + (size_t)(w + 1) * 32768; p.Hob = hs1b + (size_t)(w + 1) * 32768;
      p.hist = histAll + (size_t)w * 32768;
    }
    return p;
  };
  auto LP = [&](int layer, int w) {
    GruP p;
    if (layer == 0) {
      p.X = x2bf + (size_t)w * 131072;
      p.Hb = ls0b + (size_t)w * 131072; p.Hf = ls0f + (size_t)w * 131072;
      p.Wbih = WihLb; p.Wbhh = WhhLb; p.Wfih = Wih_l; p.Wfhh = Whh_l;
      p.bih = bih_l; p.bhh = bhh_l;
      p.Hof = ls0f + (size_t)(w + 1) * 131072; p.Hob = ls0b + (size_t)(w + 1) * 131072;
      p.hist = nullptr;
    } else {
      p.X = ls0b + (size_t)(w + 1) * 131072;
      p.Hb = ls1b + (size_t)w * 131072; p.Hf = ls1f + (size_t)w * 131072;
      p.Wbih = WihLb ? WihLb + LW : nullptr; p.Wbhh = WhhLb ? WhhLb + LW : nullptr;
      p.Wfih = Wih_l + LW; p.Wfhh = Whh_l + LW;
      p.bih = bih_l + 3072; p.bhh = bhh_l + 3072;
      p.Hof = ls1f + (size_t)(w + 1) * 131072; p.Hob = ls1b + (size_t)(w + 1) * 131072;
      p.hist = nullptr;
    }
    return p;
  };

  // ---- high chain: 17 dispatches (L1(w-1) paired with L0(w)) ----
  gru_dual<<<dim3(64, 1), 256, 0, stream>>>(HP(0, 0), HP(0, 0), 1, wbfW);
  for (int d = 1; d <= 15; ++d)
    gru_dual<<<dim3(64, 2), 256, 0, stream>>>(HP(1, d - 1), HP(0, d), 1, wbfW);
  gru_dual<<<dim3(64, 1), 256, 0, stream>>>(HP(1, 15), HP(1, 15), 1, wbfW);

  // ---- batched mid-section (all 16 blocks at once) ----
  if (packW) {
    gemm_lds<0, 1, 0, 0><<<96, 256, 0, stream>>>(histAll, KVp, nullptr, kvhAll, nullptr, 3072, 4);
  } else {
    gemm2<2, 2, 2><<<dim3(32, 16), 128, 0, stream>>>(
        histAll, 1024, Wk, 1024, 0, 0, nullptr, 0, kvhAll, nullptr, 3072, 1024);
    gemm2<2, 2, 2><<<dim3(32, 16), 128, 0, stream>>>(
        histAll, 1024, Wv, 1024, 0, 0, nullptr, 0, kvhAll + 1024, nullptr, 3072, 1024);
    gemm2<2, 2, 2><<<dim3(32, 16), 128, 0, stream>>>(
        histAll, 1024, Win, 2048, 1024, 0, nullptr, 0, kvhAll + 2048, nullptr, 3072, 1024);
  }
  inp_all<<<8192, 256, 0, stream>>>(einp, kvhAll, bin_, inpb, inpbf);
  if (packW)
    gemm_lds<0, 1, 0, 0><<<128, 256, 0, stream>>>(inpbf, WqB, nullptr, qb, nullptr, 1024, 16);
  else
    gemm2<2, 2, 2><<<dim3(32, 64), 128, 0, stream>>>(
        inpbf, 1024, Wq, 1024, 0, 0, nullptr, 0, qb, nullptr, 1024, 1024);
  attn_all<<<2048, 64, 0, stream>>>(qb, kvhAll, ctxbf);
  if (packW)
    gemm_lds<0, 0, 1, 1><<<128, 256, 0, stream>>>(ctxbf, WoB, inpb, nullptr, x2bf, 1024, 16);
  else
    gemm2<2, 2, 2><<<dim3(32, 64), 128, 0, stream>>>(
        ctxbf, 1024, Wo, 1024, 0, 0, inpb, 1024, nullptr, x2bf, 1024, 1024);

  // ---- low chain: 17 dispatches (l1(w-1) paired with l0(w)) ----
  gru_dual<<<dim3(64, 4), 256, 0, stream>>>(LP(0, 0), LP(0, 0), 4, wbfW);
  for (int d = 1; d <= 15; ++d)
    gru_dual<<<dim3(64, 8), 256, 0, stream>>>(LP(1, d - 1), LP(0, d), 4, wbfW);
  gru_dual<<<dim3(64, 4), 256, 0, stream>>>(LP(1, 15), LP(1, 15), 4, wbfW);

  // ---- layernorm (all blocks) + final projection ----
  ln_all<<<2048, 256, 0, stream>>>(ls1f, ln_g, ln_b, Ybf);
  if (packWout)
    gemm_lds<1, 1, 0, 0><<<4000, 256, 0, stream>>>(Ybf, WoutB, nullptr, out, nullptr, 32000, 16);
  else
    gemm_big<<<dim3(8, 500), 256, 0, stream>>>(Ybf, Wout, 0, out);
}

// Round 5
// 1080.873 us; speedup vs baseline: 10.6490x; 1.0256x over previous
//
#include <hip/hip_runtime.h>

typedef unsigned short u16;
typedef float f32x4 __attribute__((ext_vector_type(4)));
typedef __bf16 bf16x8 __attribute__((ext_vector_type(8)));
typedef u16 u16x8 __attribute__((ext_vector_type(8)));

#define DEVFN __device__ __forceinline__

// B=8, S=256, V=32000, H=1024, HEADS=8, HD=128, N_HIGH=4, N_LOW=16, RATIO=4
// Block = 16 timesteps; 16 blocks. Row layout R(t,b) = (w*16 + o*4 + g)*8 + b,
// w=t/16, g=(t%16)/4, o=t%4. High rows = first 32 of each 128-row block.
// States stored per block-index: state[k] = state after block k-1 (state[0]=0).

DEVFN u16 f2bf(float f) {
  unsigned u = __builtin_bit_cast(unsigned, f);
  unsigned r = u + 0x7FFFu + ((u >> 16) & 1u);   // RNE
  return (u16)(r >> 16);
}

DEVFN bf16x8 cvt8(const float* p) {
  float4 f0 = *reinterpret_cast<const float4*>(p);
  float4 f1 = *reinterpret_cast<const float4*>(p + 4);
  u16x8 u;
  u[0] = f2bf(f0.x); u[1] = f2bf(f0.y); u[2] = f2bf(f0.z); u[3] = f2bf(f0.w);
  u[4] = f2bf(f1.x); u[5] = f2bf(f1.y); u[6] = f2bf(f1.z); u[7] = f2bf(f1.w);
  return __builtin_bit_cast(bf16x8, u);
}

DEVFN bf16x8 ldbf(const u16* p) { return *reinterpret_cast<const bf16x8*>(p); }
DEVFN float sigm(float x) { return 1.f / (1.f + expf(-x)); }

DEVFN void gload16(const u16* g, u16* l) {
  __builtin_amdgcn_global_load_lds(
      (const __attribute__((address_space(1))) void*)g,
      (__attribute__((address_space(3))) void*)l, 16, 0, 0);
}

// ============ LDS-staged 128x128 GEMM, BK=32, 2-phase pipeline =====================
// OUT[M][N] = A[M][1024](bf16) @ W[N][1024](bf16)^T. 256 thr = 4 waves, each 64x64.
// XCD-bijective swizzle, M-fastest within chunk (W-panel stays in one XCD's L2).
// LDS swizzle: 16B-slot s of row r holds global col-group (s ^ ((r>>1)&3)).
// Even rows -> bank-quads 0-3, odd rows -> 4-7 => 2 lanes/quad on ds_read (free).
template<int NTSTORE, int OUTF, int BF16OUT, int CADD>
__global__ __launch_bounds__(256) void gemm_lds(
    const u16* __restrict__ A, const u16* __restrict__ W,
    const float* __restrict__ Cadd,
    float* __restrict__ OUT, u16* __restrict__ OUTbf,
    int ldo, int mtiles) {
  __shared__ u16 smA[2][128 * 32];
  __shared__ u16 smB[2][128 * 32];

  int nwg = gridDim.x;
  int orig = blockIdx.x;
  int q = nwg >> 3, r = nwg & 7;
  int xcd = orig & 7, idx = orig >> 3;
  int wg = (xcd < r ? xcd * (q + 1) : r * (q + 1) + (xcd - r) * q) + idx;
  int m0 = (wg % mtiles) * 128;
  int n0 = (wg / mtiles) * 128;

  int tid = threadIdx.x;
  int wv = tid >> 6, lane = tid & 63;
  int lrow = lane >> 2;                            // 0..15 (row within 16-row group)
  int gcol = ((lane & 3) ^ ((lrow >> 1) & 3)) << 3; // pre-swizzled global col-group

  const u16* gA = A + (size_t)(m0 + wv * 32 + lrow) * 1024 + gcol;
  const u16* gB = W + (size_t)(n0 + wv * 32 + lrow) * 1024 + gcol;
  u16* lA0 = &smA[0][(wv * 32) * 32];
  u16* lA1 = &smA[0][(wv * 32 + 16) * 32];
  u16* lB0 = &smB[0][(wv * 32) * 32];
  u16* lB1 = &smB[0][(wv * 32 + 16) * 32];
  const int BUFO = 128 * 32;                       // elems per buffer

  f32x4 acc[4][4];
#pragma unroll
  for (int mi = 0; mi < 4; ++mi)
#pragma unroll
    for (int ni = 0; ni < 4; ++ni) acc[mi][ni] = f32x4{0.f, 0.f, 0.f, 0.f};

  int qm = (wv >> 1) * 64, qn = (wv & 1) * 64;
  int lr = lane & 15;
  int kk = (lane >> 4) << 3;

  // hoisted swizzled LDS byte offsets (compile-time indexed -> registers)
  int offA[4], offB[4];
#pragma unroll
  for (int i = 0; i < 4; ++i) {
    int ra = qm + i * 16 + lr;
    offA[i] = ra * 64 + ((kk ^ (((ra >> 1) & 3) << 3)) << 1);
    int rbw = qn + i * 16 + lr;
    offB[i] = rbw * 64 + ((kk ^ (((rbw >> 1) & 3) << 3)) << 1);
  }
  const char* baseA = (const char*)&smA[0][0];
  const char* baseB = (const char*)&smB[0][0];

  // stage(kt=0, buf=0)
  gload16(gA, lA0);
  gload16(gA + 16 * 1024, lA1);
  gload16(gB, lB0);
  gload16(gB + 16 * 1024, lB1);

  for (int kt = 0; kt < 32; ++kt) {
    int buf = kt & 1;
    __syncthreads();                               // stage(kt) ready
    if (kt < 31) {                                 // issue stage(kt+1) -> other buffer
      int k0 = (kt + 1) << 5;
      int bo = (buf ^ 1) * BUFO;
      gload16(gA + k0, lA0 + bo);
      gload16(gA + 16 * 1024 + k0, lA1 + bo);
      gload16(gB + k0, lB0 + bo);
      gload16(gB + 16 * 1024 + k0, lB1 + bo);
    }
    int bb = buf * (BUFO * 2);                     // byte offset of buffer
    bf16x8 av[4], bv[4];
#pragma unroll
    for (int i = 0; i < 4; ++i) {
      av[i] = *(const bf16x8*)(baseA + bb + offA[i]);
      bv[i] = *(const bf16x8*)(baseB + bb + offB[i]);
    }
#pragma unroll
    for (int mi = 0; mi < 4; ++mi)
#pragma unroll
      for (int ni = 0; ni < 4; ++ni)
        acc[mi][ni] = __builtin_amdgcn_mfma_f32_16x16x32_bf16(av[mi], bv[ni], acc[mi][ni], 0, 0, 0);
  }

  int rb = (lane >> 4) << 2;
#pragma unroll
  for (int mi = 0; mi < 4; ++mi)
#pragma unroll
    for (int ni = 0; ni < 4; ++ni)
#pragma unroll
      for (int rr = 0; rr < 4; ++rr) {
        int row = m0 + qm + mi * 16 + rb + rr;
        int col = n0 + qn + ni * 16 + lr;
        size_t o = (size_t)row * (size_t)ldo + col;
        float v = acc[mi][ni][rr];
        if constexpr (CADD) v += Cadd[o];
        if constexpr (OUTF) {
          if constexpr (NTSTORE) __builtin_nontemporal_store(v, &OUT[o]);
          else OUT[o] = v;
        }
        if constexpr (BF16OUT) OUTbf[o] = f2bf(v);
      }
}

// ---------------- generic GEMM (fallback, fp32-weight capable) ----------------------
template<int MT, int NT, int KW>
__global__ __launch_bounds__(64 * KW) void gemm2(
    const u16* __restrict__ A, int lda,
    const void* __restrict__ Wp, int ldw, int kwoff, int wbf,
    const float* __restrict__ Cadd, int ldc,
    float* __restrict__ OUT, u16* __restrict__ OUTbf, int ldo, int K) {
  int tid = threadIdx.x;
  int kw = tid >> 6;
  int lane = tid & 63;
  int lr = lane & 15;
  int kk = (lane >> 4) << 3;
  int n0 = blockIdx.x * (16 * NT);
  int m0 = blockIdx.y * (16 * MT);
  int KP = K / KW;
  int kb = kw * KP + kk;

  f32x4 acc[MT][NT];
#pragma unroll
  for (int mi = 0; mi < MT; ++mi)
#pragma unroll
    for (int ni = 0; ni < NT; ++ni) acc[mi][ni] = f32x4{0.f, 0.f, 0.f, 0.f};

  const u16* ap[MT];
#pragma unroll
  for (int mi = 0; mi < MT; ++mi) ap[mi] = A + (size_t)(m0 + mi * 16 + lr) * (size_t)lda + kb;

  if (wbf) {
    const u16* wb[NT];
#pragma unroll
    for (int ni = 0; ni < NT; ++ni)
      wb[ni] = (const u16*)Wp + (size_t)(n0 + ni * 16 + lr) * (size_t)ldw + kwoff + kb;
    for (int k0 = 0; k0 < KP; k0 += 32) {
      bf16x8 wv[NT];
#pragma unroll
      for (int ni = 0; ni < NT; ++ni) wv[ni] = ldbf(wb[ni] + k0);
#pragma unroll
      for (int mi = 0; mi < MT; ++mi) {
        bf16x8 a = ldbf(ap[mi] + k0);
#pragma unroll
        for (int ni = 0; ni < NT; ++ni)
          acc[mi][ni] = __builtin_amdgcn_mfma_f32_16x16x32_bf16(a, wv[ni], acc[mi][ni], 0, 0, 0);
      }
    }
  } else {
    const float* wf[NT];
#pragma unroll
    for (int ni = 0; ni < NT; ++ni)
      wf[ni] = (const float*)Wp + (size_t)(n0 + ni * 16 + lr) * (size_t)ldw + kwoff + kb;
    for (int k0 = 0; k0 < KP; k0 += 32) {
      bf16x8 wv[NT];
#pragma unroll
      for (int ni = 0; ni < NT; ++ni) wv[ni] = cvt8(wf[ni] + k0);
#pragma unroll
      for (int mi = 0; mi < MT; ++mi) {
        bf16x8 a = ldbf(ap[mi] + k0);
#pragma unroll
        for (int ni = 0; ni < NT; ++ni)
          acc[mi][ni] = __builtin_amdgcn_mfma_f32_16x16x32_bf16(a, wv[ni], acc[mi][ni], 0, 0, 0);
      }
    }
  }

  if constexpr (KW > 1) {
    __shared__ f32x4 red[KW][MT * NT][64];
#pragma unroll
    for (int mi = 0; mi < MT; ++mi)
#pragma unroll
      for (int ni = 0; ni < NT; ++ni) red[kw][mi * NT + ni][lane] = acc[mi][ni];
    __syncthreads();
    if (kw) return;
    for (int w2 = 1; w2 < KW; ++w2)
#pragma unroll
      for (int mi = 0; mi < MT; ++mi)
#pragma unroll
        for (int ni = 0; ni < NT; ++ni) acc[mi][ni] += red[w2][mi * NT + ni][lane];
  }

  int rb = (lane >> 4) << 2;
#pragma unroll
  for (int mi = 0; mi < MT; ++mi)
#pragma unroll
    for (int ni = 0; ni < NT; ++ni)
#pragma unroll
      for (int rr = 0; rr < 4; ++rr) {
        int row = m0 + mi * 16 + rb + rr;
        int col = n0 + ni * 16 + lr;
        size_t o = (size_t)row * (size_t)ldo + col;
        float v = acc[mi][ni][rr];
        if (Cadd) v += Cadd[(size_t)row * (size_t)ldc + col];
        if (OUT) OUT[o] = v;
        if (OUTbf) OUTbf[o] = f2bf(v);
      }
}

// ---------------- dual-problem fused GRU layer --------------------------------------
struct GruP {
  const u16* X; const u16* Hb; const float* Hf;
  const u16* Wbih; const u16* Wbhh;
  const float* Wfih; const float* Wfhh;
  const float* bih; const float* bhh;
  float* Hof; u16* Hob; u16* hist;
};

__global__ __launch_bounds__(256) void gru_dual(GruP pa, GruP pb, int tiles1, int wbf) {
  GruP p; int m0;
  if ((int)blockIdx.y < tiles1) { p = pa; m0 = blockIdx.y * 32; }
  else { p = pb; m0 = ((int)blockIdx.y - tiles1) * 32; }
  int tid = threadIdx.x;
  int kw = tid >> 6;
  int lane = tid & 63;
  int lr = lane & 15;
  int kk = (lane >> 4) << 3;
  int j0 = blockIdx.x * 16;
  const int KP = 256;
  int kb = kw * KP + kk;

  f32x4 aR[2], aZ[2], aNX[2], aNH[2];
#pragma unroll
  for (int mi = 0; mi < 2; ++mi) {
    aR[mi] = f32x4{0.f, 0.f, 0.f, 0.f};
    aZ[mi] = f32x4{0.f, 0.f, 0.f, 0.f};
    aNX[mi] = f32x4{0.f, 0.f, 0.f, 0.f};
    aNH[mi] = f32x4{0.f, 0.f, 0.f, 0.f};
  }

  const u16* xp[2];
  const u16* hp[2];
#pragma unroll
  for (int mi = 0; mi < 2; ++mi) {
    size_t ro = (size_t)(m0 + mi * 16 + lr) * 1024 + kb;
    xp[mi] = p.X + ro;
    hp[mi] = p.Hb + ro;
  }

  size_t wro = (size_t)(j0 + lr) * 1024 + kb;
  if (wbf) {
    const u16 *pxr = p.Wbih + wro, *pxz = p.Wbih + wro + 1048576, *pxn = p.Wbih + wro + 2097152;
    const u16 *phr = p.Wbhh + wro, *phz = p.Wbhh + wro + 1048576, *phn = p.Wbhh + wro + 2097152;
    for (int k0 = 0; k0 < KP; k0 += 32) {
      bf16x8 wxr = ldbf(pxr + k0), wxz = ldbf(pxz + k0), wxn = ldbf(pxn + k0);
      bf16x8 whr = ldbf(phr + k0), whz = ldbf(phz + k0), whn = ldbf(phn + k0);
#pragma unroll
      for (int mi = 0; mi < 2; ++mi) {
        bf16x8 ax = ldbf(xp[mi] + k0);
        bf16x8 ah = ldbf(hp[mi] + k0);
        aR[mi] = __builtin_amdgcn_mfma_f32_16x16x32_bf16(ax, wxr, aR[mi], 0, 0, 0);
        aR[mi] = __builtin_amdgcn_mfma_f32_16x16x32_bf16(ah, whr, aR[mi], 0, 0, 0);
        aZ[mi] = __builtin_amdgcn_mfma_f32_16x16x32_bf16(ax, wxz, aZ[mi], 0, 0, 0);
        aZ[mi] = __builtin_amdgcn_mfma_f32_16x16x32_bf16(ah, whz, aZ[mi], 0, 0, 0);
        aNX[mi] = __builtin_amdgcn_mfma_f32_16x16x32_bf16(ax, wxn, aNX[mi], 0, 0, 0);
        aNH[mi] = __builtin_amdgcn_mfma_f32_16x16x32_bf16(ah, whn, aNH[mi], 0, 0, 0);
      }
    }
  } else {
    const float *pxr = p.Wfih + wro, *pxz = p.Wfih + wro + 1048576, *pxn = p.Wfih + wro + 2097152;
    const float *phr = p.Wfhh + wro, *phz = p.Wfhh + wro + 1048576, *phn = p.Wfhh + wro + 2097152;
    for (int k0 = 0; k0 < KP; k0 += 32) {
      bf16x8 wxr = cvt8(pxr + k0), wxz = cvt8(pxz + k0), wxn = cvt8(pxn + k0);
      bf16x8 whr = cvt8(phr + k0), whz = cvt8(phz + k0), whn = cvt8(phn + k0);
#pragma unroll
      for (int mi = 0; mi < 2; ++mi) {
        bf16x8 ax = ldbf(xp[mi] + k0);
        bf16x8 ah = ldbf(hp[mi] + k0);
        aR[mi] = __builtin_amdgcn_mfma_f32_16x16x32_bf16(ax, wxr, aR[mi], 0, 0, 0);
        aR[mi] = __builtin_amdgcn_mfma_f32_16x16x32_bf16(ah, whr, aR[mi], 0, 0, 0);
        aZ[mi] = __builtin_amdgcn_mfma_f32_16x16x32_bf16(ax, wxz, aZ[mi], 0, 0, 0);
        aZ[mi] = __builtin_amdgcn_mfma_f32_16x16x32_bf16(ah, whz, aZ[mi], 0, 0, 0);
        aNX[mi] = __builtin_amdgcn_mfma_f32_16x16x32_bf16(ax, wxn, aNX[mi], 0, 0, 0);
        aNH[mi] = __builtin_amdgcn_mfma_f32_16x16x32_bf16(ah, whn, aNH[mi], 0, 0, 0);
      }
    }
  }

  {
    __shared__ f32x4 red[4][8][64];
#pragma unroll
    for (int mi = 0; mi < 2; ++mi) {
      red[kw][mi * 4 + 0][lane] = aR[mi];
      red[kw][mi * 4 + 1][lane] = aZ[mi];
      red[kw][mi * 4 + 2][lane] = aNX[mi];
      red[kw][mi * 4 + 3][lane] = aNH[mi];
    }
    __syncthreads();
    if (kw) return;
    for (int w2 = 1; w2 < 4; ++w2)
#pragma unroll
      for (int mi = 0; mi < 2; ++mi) {
        aR[mi] += red[w2][mi * 4 + 0][lane];
        aZ[mi] += red[w2][mi * 4 + 1][lane];
        aNX[mi] += red[w2][mi * 4 + 2][lane];
        aNH[mi] += red[w2][mi * 4 + 3][lane];
      }
  }

  int c = j0 + lr;
  float br = p.bih[c] + p.bhh[c];
  float bz = p.bih[1024 + c] + p.bhh[1024 + c];
  float bnx = p.bih[2048 + c];
  float bnh = p.bhh[2048 + c];
  int rb = (lane >> 4) << 2;
#pragma unroll
  for (int mi = 0; mi < 2; ++mi)
#pragma unroll
    for (int rr = 0; rr < 4; ++rr) {
      int row = m0 + mi * 16 + rb + rr;
      float r = sigm(aR[mi][rr] + br);
      float z = sigm(aZ[mi][rr] + bz);
      float n = tanhf(aNX[mi][rr] + bnx + r * (aNH[mi][rr] + bnh));
      size_t o = (size_t)row * 1024 + c;
      float hv = (1.f - z) * n + z * p.Hf[o];
      p.Hof[o] = hv;
      u16 hb = f2bf(hv);
      p.Hob[o] = hb;
      if (p.hist) p.hist[o] = hb;
    }
}

// ---------------- final projection fallback (fp32 W, direct) ------------------------
__global__ __launch_bounds__(256) void gemm_big(const u16* __restrict__ A,
                                                const void* __restrict__ Wp, int wbf,
                                                float* __restrict__ OUT) {
  int wv = threadIdx.x >> 6;
  int lane = threadIdx.x & 63;
  int lr = lane & 15;
  int kk = (lane >> 4) << 3;
  int m0 = blockIdx.x * 256 + wv * 64;
  int n0 = blockIdx.y * 64;

  f32x4 acc[4][4];
#pragma unroll
  for (int mi = 0; mi < 4; ++mi)
#pragma unroll
    for (int ni = 0; ni < 4; ++ni) acc[mi][ni] = f32x4{0.f, 0.f, 0.f, 0.f};

  const u16* ap[4];
#pragma unroll
  for (int mi = 0; mi < 4; ++mi) ap[mi] = A + (size_t)(m0 + mi * 16 + lr) * 1024 + kk;

  const float* wf[4];
#pragma unroll
  for (int ni = 0; ni < 4; ++ni) wf[ni] = (const float*)Wp + (size_t)(n0 + ni * 16 + lr) * 1024 + kk;
  for (int k0 = 0; k0 < 1024; k0 += 32) {
    bf16x8 wvv[4];
#pragma unroll
    for (int ni = 0; ni < 4; ++ni) wvv[ni] = cvt8(wf[ni] + k0);
#pragma unroll
    for (int mi = 0; mi < 4; ++mi) {
      bf16x8 a = ldbf(ap[mi] + k0);
#pragma unroll
      for (int ni = 0; ni < 4; ++ni)
        acc[mi][ni] = __builtin_amdgcn_mfma_f32_16x16x32_bf16(a, wvv[ni], acc[mi][ni], 0, 0, 0);
    }
  }

  int rb = (lane >> 4) << 2;
#pragma unroll
  for (int mi = 0; mi < 4; ++mi)
#pragma unroll
    for (int ni = 0; ni < 4; ++ni)
#pragma unroll
      for (int rr = 0; rr < 4; ++rr) {
        size_t o = (size_t)(m0 + mi * 16 + rb + rr) * 32000 + (size_t)(n0 + ni * 16 + lr);
        __builtin_nontemporal_store(acc[mi][ni][rr], &OUT[o]);
      }
}

// ---------------- fused fp32 -> bf16 weight pack (all matrices, one dispatch) -------
struct CvtSeg { const float* src; u16* dst; int src_ld; int col_off; int log2c; int nblk; };
struct CvtArgs { CvtSeg seg[11]; int nseg; };

__global__ void cvt_all(CvtArgs a) {
  int blk = blockIdx.x;
  int s = 0;
  while (s < a.nseg - 1 && blk >= a.seg[s].nblk) { blk -= a.seg[s].nblk; ++s; }
  const CvtSeg g = a.seg[s];
  size_t idx = ((size_t)blk * 256 + threadIdx.x) * 8;
  size_t row = idx >> g.log2c;
  int col = (int)(idx & ((1u << g.log2c) - 1));
  const float* sp = g.src + row * (size_t)g.src_ld + g.col_off + col;
  *reinterpret_cast<u16x8*>(g.dst + idx) = __builtin_bit_cast(u16x8, cvt8(sp));
}

// ---------------- embeds (bf16) -----------------------------------------------------
__global__ void embed_kernel(const int* __restrict__ ids, const float* __restrict__ emb,
                             const float* __restrict__ pos, u16* __restrict__ out) {
  int idx = blockIdx.x * 256 + threadIdx.x;
  int e8 = (idx & 127) << 3;
  int rb = idx >> 7;
  int t = rb >> 3, b = rb & 7;
  int w = t >> 4, lsp = t & 15, g = lsp >> 2, o = lsp & 3;
  int R = ((w << 4) + (o << 2) + g) * 8 + b;
  int tok = ids[b * 256 + t];
  const float* ep = emb + (size_t)tok * 1024 + e8;
  const float* pp = pos + (size_t)t * 1024 + e8;
  u16x8 u;
#pragma unroll
  for (int i = 0; i < 8; ++i) u[i] = f2bf(ep[i] + pp[i]);
  *reinterpret_cast<u16x8*>(out + (size_t)R * 1024 + e8) = u;
}

// ---------------- batched inp = gelu(einp + hc + bin) -------------------------------
__global__ void inp_all(const float* __restrict__ einp, const float* __restrict__ kvhAll,
                        const float* __restrict__ bin, float* __restrict__ inpb,
                        u16* __restrict__ inpbf) {
  int idx = blockIdx.x * 256 + threadIdx.x;   // 2048*1024
  int r = idx >> 10, j = idx & 1023;
  int w = r >> 7, r7 = r & 127;
  int g = (r7 >> 3) & 3, b = r7 & 7;
  float x = einp[idx] + kvhAll[(size_t)(w * 32 + g * 8 + b) * 3072 + 2048 + j] + bin[j];
  float t = tanhf(0.7978845608028654f * (x + 0.044715f * x * x * x));
  float v = 0.5f * x * (1.f + t);
  inpb[idx] = v;
  inpbf[idx] = f2bf(v);
}

// ---------------- batched attention -------------------------------------------------
__global__ void attn_all(const float* __restrict__ qb, const float* __restrict__ kvhAll,
                         u16* __restrict__ ctxbf) {
  int r = blockIdx.x;        // 0..2047
  int w = r >> 7, r7 = r & 127;
  int sp = r7 >> 3;
  int g = sp & 3;
  int b = r7 & 7;
  int lane = threadIdx.x;
  const float* kvb = kvhAll + (size_t)w * 32 * 3072;
  __shared__ float aw[8][4];
  if (lane < 32) {
    int head = lane >> 2, t = lane & 3;
    float s = 0.f;
    if (t <= g) {
      const float* qp = qb + (size_t)r * 1024 + head * 128;
      const float* kp = kvb + (size_t)(t * 8 + b) * 3072 + head * 128;
      for (int d = 0; d < 128; ++d) s += qp[d] * kp[d];
      s *= 0.08838834764831845f;
    }
    float sc[4];
    sc[0] = __shfl(s, (head << 2) + 0);
    sc[1] = __shfl(s, (head << 2) + 1);
    sc[2] = __shfl(s, (head << 2) + 2);
    sc[3] = __shfl(s, (head << 2) + 3);
    if (t == 0) {
      float mx = -1e30f;
      for (int u = 0; u <= g; ++u) mx = fmaxf(mx, sc[u]);
      float p[4] = {0.f, 0.f, 0.f, 0.f};
      float den = 0.f;
      for (int u = 0; u <= g; ++u) { p[u] = expf(sc[u] - mx); den += p[u]; }
      float inv = 1.f / den;
      for (int u = 0; u < 4; ++u) aw[head][u] = (u <= g) ? p[u] * inv : 0.f;
    }
  }
  __syncthreads();
  for (int idx = lane; idx < 1024; idx += 64) {
    int head = idx >> 7;
    float acc = 0.f;
#pragma unroll
    for (int t = 0; t < 4; ++t) acc += aw[head][t] * kvb[(size_t)(t * 8 + b) * 3072 + 1024 + idx];
    ctxbf[(size_t)r * 1024 + idx] = f2bf(acc);
  }
}

// ---------------- batched layernorm -> bf16 Y ---------------------------------------
__global__ void ln_all(const float* __restrict__ ls1f, const float* __restrict__ g_,
                       const float* __restrict__ b_, u16* __restrict__ Ybf) {
  int bid = blockIdx.x;      // 0..2047
  int w = bid >> 7, r7 = bid & 127;
  int tid = threadIdx.x;     // 256
  const float* x = ls1f + (size_t)(w + 1) * 131072 + (size_t)r7 * 1024;
  float s = 0.f, s2 = 0.f;
  for (int j = tid; j < 1024; j += 256) { float v = x[j]; s += v; s2 += v * v; }
  for (int off = 32; off; off >>= 1) { s += __shfl_xor(s, off); s2 += __shfl_xor(s2, off); }
  __shared__ float rs[4], rs2[4], mv[2];
  int wv = tid >> 6;
  if ((tid & 63) == 0) { rs[wv] = s; rs2[wv] = s2; }
  __syncthreads();
  if (tid == 0) {
    float S = rs[0] + rs[1] + rs[2] + rs[3];
    float S2 = rs2[0] + rs2[1] + rs2[2] + rs2[3];
    float mu = S * (1.f / 1024.f);
    float var = S2 * (1.f / 1024.f) - mu * mu;
    mv[0] = mu;
    mv[1] = rsqrtf(var + 1e-5f);
  }
  __syncthreads();
  float mu = mv[0], rstd = mv[1];
  int sp = r7 >> 3, b = r7 & 7;
  int g = sp & 3, o = sp >> 2;
  int t = w * 16 + g * 4 + o;
  u16* yrow = Ybf + (size_t)(b * 256 + t) * 1024;
  for (int j = tid; j < 1024; j += 256) {
    float v = (x[j] - mu) * rstd * g_[j] + b_[j];
    yrow[j] = f2bf(v);
  }
}

extern "C" void kernel_launch(void* const* d_in, const int* in_sizes, int n_in,
                              void* d_out, int out_size, void* d_ws, size_t ws_size,
                              hipStream_t stream) {
  const int* ids = (const int*)d_in[0];
  const float* emb = (const float*)d_in[1];
  const float* pos = (const float*)d_in[2];
  const float* Wih_h = (const float*)d_in[3];
  const float* bih_h = (const float*)d_in[4];
  const float* Whh_h = (const float*)d_in[5];
  const float* bhh_h = (const float*)d_in[6];
  const float* Win = (const float*)d_in[7];
  const float* bin_ = (const float*)d_in[8];
  const float* Wq = (const float*)d_in[9];
  const float* Wk = (const float*)d_in[10];
  const float* Wv = (const float*)d_in[11];
  const float* Wo = (const float*)d_in[12];
  const float* Wih_l = (const float*)d_in[13];
  const float* bih_l = (const float*)d_in[14];
  const float* Whh_l = (const float*)d_in[15];
  const float* bhh_l = (const float*)d_in[16];
  const float* ln_g = (const float*)d_in[17];
  const float* ln_b = (const float*)d_in[18];
  const float* Wout = (const float*)d_in[19];
  float* out = (float*)d_out;

  // ---- workspace bump allocator ----
  size_t off = 0;
  char* wsb = (char*)d_ws;
  auto allocF = [&](size_t n) { float* p = (float*)(wsb + off); off += n * 4; return p; };
  auto allocU = [&](size_t n) { u16* p = (u16*)(wsb + off); off += n * 2; return p; };

  // per-block-index state arrays [17]
  float* hs0f = allocF((size_t)17 * 32768);
  float* hs1f = allocF((size_t)17 * 32768);
  float* ls0f = allocF((size_t)17 * 131072);
  float* ls1f = allocF((size_t)17 * 131072);
  u16* hs0b = allocU((size_t)17 * 32768);
  u16* hs1b = allocU((size_t)17 * 32768);
  u16* ls0b = allocU((size_t)17 * 131072);
  u16* ls1b = allocU((size_t)17 * 131072);
  u16* histAll = allocU(524288);          // [16][32][1024]
  u16* embB = allocU(2097152);
  float* einp = allocF(2097152);
  float* kvhAll = allocF((size_t)512 * 3072);
  float* inpb = allocF(2097152);
  u16* inpbf = allocU(2097152);
  float* qb = allocF(2097152);
  u16* ctxbf = allocU(2097152);
  u16* x2bf = allocU(2097152);
  u16* Ybf = allocU(2097152);

  const size_t WPACK_BYTES = (size_t)(4 * 6291456 + 1048576 + 1048576 + 1048576 + 3145728) * 2;
  bool packW = (off + WPACK_BYTES <= ws_size);
  u16 *WihHb = nullptr, *WhhHb = nullptr, *WihLb = nullptr, *WhhLb = nullptr;
  u16 *WinB0 = nullptr, *WqB = nullptr, *WoB = nullptr, *KVp = nullptr;
  if (packW) {
    WihHb = allocU(6291456);
    WhhHb = allocU(6291456);
    WihLb = allocU(6291456);
    WhhLb = allocU(6291456);
    WinB0 = allocU(1048576);   // Win[:, :1024] as [1024][1024]
    WqB = allocU(1048576);
    WoB = allocU(1048576);
    KVp = allocU(3145728);     // Wk | Wv | Win[:, 1024:]
  }
  bool packWout = packW && (off + (size_t)32768000 * 2 <= ws_size);
  u16* WoutB = nullptr;
  if (packWout) WoutB = allocU(32768000);

  // zero initial states (index 0 slices, fp32 + bf16)
  (void)hipMemsetAsync(hs0f, 0, 32768 * 4, stream);
  (void)hipMemsetAsync(hs1f, 0, 32768 * 4, stream);
  (void)hipMemsetAsync(ls0f, 0, 131072 * 4, stream);
  (void)hipMemsetAsync(ls1f, 0, 131072 * 4, stream);
  (void)hipMemsetAsync(hs0b, 0, 32768 * 2, stream);
  (void)hipMemsetAsync(hs1b, 0, 32768 * 2, stream);
  (void)hipMemsetAsync(ls0b, 0, 131072 * 2, stream);
  (void)hipMemsetAsync(ls1b, 0, 131072 * 2, stream);

  // ---- prologue ----
  embed_kernel<<<1024, 256, 0, stream>>>(ids, emb, pos, embB);
  if (packW) {
    CvtArgs ca{};
    int ns = 0, tot = 0;
    auto add = [&](const float* s, u16* d, int ld, int co, int l2c, size_t nelem) {
      int nb = (int)(nelem / 2048);
      ca.seg[ns++] = CvtSeg{s, d, ld, co, l2c, nb};
      tot += nb;
    };
    add(Wih_h, WihHb, 1024, 0, 10, 6291456);
    add(Whh_h, WhhHb, 1024, 0, 10, 6291456);
    add(Wih_l, WihLb, 1024, 0, 10, 6291456);
    add(Whh_l, WhhLb, 1024, 0, 10, 6291456);
    add(Win, WinB0, 2048, 0, 10, 1048576);
    add(Wq, WqB, 1024, 0, 10, 1048576);
    add(Wo, WoB, 1024, 0, 10, 1048576);
    add(Wk, KVp, 1024, 0, 10, 1048576);
    add(Wv, KVp + 1048576, 1024, 0, 10, 1048576);
    add(Win, KVp + 2097152, 2048, 1024, 10, 1048576);
    if (packWout) add(Wout, WoutB, 1024, 0, 10, 32768000);
    ca.nseg = ns;
    cvt_all<<<tot, 256, 0, stream>>>(ca);
  }
  int wbfW = packW ? 1 : 0;

  // einp = embeds @ Win[:, :1024]^T (all 2048 rows)
  if (packW)
    gemm_lds<0, 1, 0, 0><<<128, 256, 0, stream>>>(embB, WinB0, nullptr, einp, nullptr, 1024, 16);
  else
    gemm2<2, 2, 2><<<dim3(32, 64), 128, 0, stream>>>(
        embB, 1024, Win, 2048, 0, 0, nullptr, 0, einp, nullptr, 1024, 1024);

  const size_t LW = (size_t)3072 * 1024;
  auto HP = [&](int layer, int w) {
    GruP p;
    if (layer == 0) {
      p.X = embB + (size_t)w * 131072;
      p.Hb = hs0b + (size_t)w * 32768; p.Hf = hs0f + (size_t)w * 32768;
      p.Wbih = WihHb; p.Wbhh = WhhHb; p.Wfih = Wih_h; p.Wfhh = Whh_h;
      p.bih = bih_h; p.bhh = bhh_h;
      p.Hof = hs0f + (size_t)(w + 1) * 32768; p.Hob = hs0b + (size_t)(w + 1) * 32768;
      p.hist = nullptr;
    } else {
      p.X = hs0b + (size_t)(w + 1) * 32768;
      p.Hb = hs1b + (size_t)w * 32768; p.Hf = hs1f + (size_t)w * 32768;
      p.Wbih = WihHb ? WihHb + LW : nullptr; p.Wbhh = WhhHb ? WhhHb + LW : nullptr;
      p.Wfih = Wih_h + LW; p.Wfhh = Whh_h + LW;
      p.bih = bih_h + 3072; p.bhh = bhh_h + 3072;
      p.Hof = hs1f + (size_t)(w + 1) * 32768; p.Hob = hs1b + (size_t)(w + 1) * 32768;
      p.hist = histAll + (size_t)w * 32768;
    }
    return p;
  };
  auto LP = [&](int layer, int w) {
    GruP p;
    if (layer == 0) {
      p.X = x2bf + (size_t)w * 131072;
      p.Hb = ls0b + (size_t)w * 131072; p.Hf = ls0f + (size_t)w * 131072;
      p.Wbih = WihLb; p.Wbhh = WhhLb; p.Wfih = Wih_l; p.Wfhh = Whh_l;
      p.bih = bih_l; p.bhh = bhh_l;
      p.Hof = ls0f + (size_t)(w + 1) * 131072; p.Hob = ls0b + (size_t)(w + 1) * 131072;
      p.hist = nullptr;
    } else {
      p.X = ls0b + (size_t)(w + 1) * 131072;
      p.Hb = ls1b + (size_t)w * 131072; p.Hf = ls1f + (size_t)w * 131072;
      p.Wbih = WihLb ? WihLb + LW : nullptr; p.Wbhh = WhhLb ? WhhLb + LW : nullptr;
      p.Wfih = Wih_l + LW; p.Wfhh = Whh_l + LW;
      p.bih = bih_l + 3072; p.bhh = bhh_l + 3072;
      p.Hof = ls1f + (size_t)(w + 1) * 131072; p.Hob = ls1b + (size_t)(w + 1) * 131072;
      p.hist = nullptr;
    }
    return p;
  };

  // ---- high chain: 17 dispatches (L1(w-1) paired with L0(w)) ----
  gru_dual<<<dim3(64, 1), 256, 0, stream>>>(HP(0, 0), HP(0, 0), 1, wbfW);
  for (int d = 1; d <= 15; ++d)
    gru_dual<<<dim3(64, 2), 256, 0, stream>>>(HP(1, d - 1), HP(0, d), 1, wbfW);
  gru_dual<<<dim3(64, 1), 256, 0, stream>>>(HP(1, 15), HP(1, 15), 1, wbfW);

  // ---- batched mid-section (all 16 blocks at once) ----
  if (packW) {
    gemm_lds<0, 1, 0, 0><<<96, 256, 0, stream>>>(histAll, KVp, nullptr, kvhAll, nullptr, 3072, 4);
  } else {
    gemm2<2, 2, 2><<<dim3(32, 16), 128, 0, stream>>>(
        histAll, 1024, Wk, 1024, 0, 0, nullptr, 0, kvhAll, nullptr, 3072, 1024);
    gemm2<2, 2, 2><<<dim3(32, 16), 128, 0, stream>>>(
        histAll, 1024, Wv, 1024, 0, 0, nullptr, 0, kvhAll + 1024, nullptr, 3072, 1024);
    gemm2<2, 2, 2><<<dim3(32, 16), 128, 0, stream>>>(
        histAll, 1024, Win, 2048, 1024, 0, nullptr, 0, kvhAll + 2048, nullptr, 3072, 1024);
  }
  inp_all<<<8192, 256, 0, stream>>>(einp, kvhAll, bin_, inpb, inpbf);
  if (packW)
    gemm_lds<0, 1, 0, 0><<<128, 256, 0, stream>>>(inpbf, WqB, nullptr, qb, nullptr, 1024, 16);
  else
    gemm2<2, 2, 2><<<dim3(32, 64), 128, 0, stream>>>(
        inpbf, 1024, Wq, 1024, 0, 0, nullptr, 0, qb, nullptr, 1024, 1024);
  attn_all<<<2048, 64, 0, stream>>>(qb, kvhAll, ctxbf);
  if (packW)
    gemm_lds<0, 0, 1, 1><<<128, 256, 0, stream>>>(ctxbf, WoB, inpb, nullptr, x2bf, 1024, 16);
  else
    gemm2<2, 2, 2><<<dim3(32, 64), 128, 0, stream>>>(
        ctxbf, 1024, Wo, 1024, 0, 0, inpb, 1024, nullptr, x2bf, 1024, 1024);

  // ---- low chain: 17 dispatches (l1(w-1) paired with l0(w)) ----
  gru_dual<<<dim3(64, 4), 256, 0, stream>>>(LP(0, 0), LP(0, 0), 4, wbfW);
  for (int d = 1; d <= 15; ++d)
    gru_dual<<<dim3(64, 8), 256, 0, stream>>>(LP(1, d - 1), LP(0, d), 4, wbfW);
  gru_dual<<<dim3(64, 4), 256, 0, stream>>>(LP(1, 15), LP(1, 15), 4, wbfW);

  // ---- layernorm (all blocks) + final projection ----
  ln_all<<<2048, 256, 0, stream>>>(ls1f, ln_g, ln_b, Ybf);
  if (packWout)
    gemm_lds<1, 1, 0, 0><<<4000, 256, 0, stream>>>(Ybf, WoutB, nullptr, out, nullptr, 32000, 16);
  else
    gemm_big<<<dim3(8, 500), 256, 0, stream>>>(Ybf, Wout, 0, out);
}